// Round 1
// baseline (3134.379 us; speedup 1.0000x reference)
//
#include <hip/hip_runtime.h>
#include <math.h>

#define NEG_SLOPE 0.2f

static __device__ __forceinline__ float atomicAddF(float* p, float v) {
  return __hip_atomic_fetch_add(p, v, __ATOMIC_RELAXED, __HIP_MEMORY_SCOPE_AGENT);
}

// float atomic max via signed-max / unsigned-min bit trick; m initialized to -inf
static __device__ __forceinline__ void atomicMaxF(float* addr, float v) {
  int iv = __float_as_int(v);
  if (iv >= 0) atomicMax((int*)addr, iv);
  else atomicMin((unsigned int*)addr, (unsigned int)iv);
}

// ---------- GEMM1: C[M,64] = A[M,512] @ B[512,64], fp32 ----------
__global__ __launch_bounds__(256) void gemm1_kernel(const float* __restrict__ A,
                                                    const float* __restrict__ B,
                                                    float* __restrict__ C, int M) {
  __shared__ float As[16][68];  // [kk][row], padded
  __shared__ float Bs[16][68];  // [kk][col], padded (16B-aligned rows)
  const int K = 512;
  int tid = threadIdx.x;
  int ty = tid >> 4, tx = tid & 15;
  int row0 = blockIdx.x << 6;
  float acc[4][4] = {};
  int la_row = tid >> 2;          // 0..63
  int la_k4  = (tid & 3) << 2;    // 0,4,8,12
  int lb_k   = tid >> 4;          // 0..15
  int lb_c4  = (tid & 15) << 2;   // 0..60
  for (int k0 = 0; k0 < K; k0 += 16) {
    float4 av = make_float4(0.f, 0.f, 0.f, 0.f);
    int ar = row0 + la_row;
    if (ar < M) av = *(const float4*)(A + (size_t)ar * K + k0 + la_k4);
    As[la_k4 + 0][la_row] = av.x;
    As[la_k4 + 1][la_row] = av.y;
    As[la_k4 + 2][la_row] = av.z;
    As[la_k4 + 3][la_row] = av.w;
    float4 bv = *(const float4*)(B + (size_t)(k0 + lb_k) * 64 + lb_c4);
    *(float4*)(&Bs[lb_k][lb_c4]) = bv;
    __syncthreads();
#pragma unroll
    for (int kk = 0; kk < 16; ++kk) {
      float4 a4 = *(const float4*)(&As[kk][ty << 2]);
      float4 b4 = *(const float4*)(&Bs[kk][tx << 2]);
      float a[4] = {a4.x, a4.y, a4.z, a4.w};
      float b[4] = {b4.x, b4.y, b4.z, b4.w};
#pragma unroll
      for (int i = 0; i < 4; ++i)
#pragma unroll
        for (int j = 0; j < 4; ++j)
          acc[i][j] += a[i] * b[j];
    }
    __syncthreads();
  }
#pragma unroll
  for (int i = 0; i < 4; ++i) {
    int r = row0 + (ty << 2) + i;
    if (r < M) {
      float4 o = make_float4(acc[i][0], acc[i][1], acc[i][2], acc[i][3]);
      *(float4*)(C + (size_t)r * 64 + (tx << 2)) = o;
    }
  }
}

// ---------- per-(node,head) attention coefs for layer 1 + state init ----------
__global__ void node1_prep(const float* __restrict__ xl,
                           const float* __restrict__ att_src, const float* __restrict__ att_dst,
                           float* __restrict__ a_src, float* __restrict__ a_dst,
                           float* __restrict__ m1, float* __restrict__ d1,
                           float* __restrict__ agg1, int N) {
  int t = blockIdx.x * blockDim.x + threadIdx.x;
  if (t >= N * 8) return;
  int n = t >> 3, h = t & 7;
  const float* xp = xl + (size_t)n * 64 + h * 8;
  float s = 0.f, d = 0.f;
#pragma unroll
  for (int c = 0; c < 8; ++c) {
    float v = xp[c];
    s += v * att_src[h * 8 + c];
    d += v * att_dst[h * 8 + c];
  }
  a_src[t] = s;
  a_dst[t] = d;
  m1[t] = -INFINITY;
  d1[t] = 0.f;
  float4 z = make_float4(0.f, 0.f, 0.f, 0.f);
  *(float4*)(agg1 + (size_t)n * 64 + h * 8) = z;
  *(float4*)(agg1 + (size_t)n * 64 + h * 8 + 4) = z;
}

// ---------- layer-1 edge passes ----------
__global__ void edge1_max(const int* __restrict__ ei, int E, int N,
                          const float* __restrict__ a_src, const float* __restrict__ a_dst,
                          float* __restrict__ m1) {
  int e = blockIdx.x * blockDim.x + threadIdx.x;
  if (e >= E + N) return;
  int s, d;
  if (e < E) { s = ei[e]; d = ei[E + e]; } else { s = d = e - E; }
#pragma unroll
  for (int h = 0; h < 8; ++h) {
    float a = a_src[s * 8 + h] + a_dst[d * 8 + h];
    a = a >= 0.f ? a : NEG_SLOPE * a;
    atomicMaxF(m1 + d * 8 + h, a);
  }
}

__global__ void edge1_sum(const int* __restrict__ ei, int E, int N,
                          const float* __restrict__ a_src, const float* __restrict__ a_dst,
                          const float* __restrict__ m1, float* __restrict__ d1) {
  int e = blockIdx.x * blockDim.x + threadIdx.x;
  if (e >= E + N) return;
  int s, d;
  if (e < E) { s = ei[e]; d = ei[E + e]; } else { s = d = e - E; }
#pragma unroll
  for (int h = 0; h < 8; ++h) {
    float a = a_src[s * 8 + h] + a_dst[d * 8 + h];
    a = a >= 0.f ? a : NEG_SLOPE * a;
    atomicAddF(d1 + d * 8 + h, __expf(a - m1[d * 8 + h]));
  }
}

__global__ void edge1_agg(const int* __restrict__ ei, int E, int N,
                          const float* __restrict__ a_src, const float* __restrict__ a_dst,
                          const float* __restrict__ m1, const float* __restrict__ d1,
                          const float* __restrict__ xl, float* __restrict__ agg1) {
  int idx = blockIdx.x * blockDim.x + threadIdx.x;
  if (idx >= (E + N) * 8) return;
  int e = idx >> 3, h = idx & 7;
  int s, d;
  if (e < E) { s = ei[e]; d = ei[E + e]; } else { s = d = e - E; }
  float a = a_src[s * 8 + h] + a_dst[d * 8 + h];
  a = a >= 0.f ? a : NEG_SLOPE * a;
  float coef = __expf(a - m1[d * 8 + h]) / (d1[d * 8 + h] + 1e-16f);
  const float* xp = xl + (size_t)s * 64 + h * 8;
  float* op = agg1 + (size_t)d * 64 + h * 8;
#pragma unroll
  for (int c = 0; c < 8; ++c) atomicAddF(op + c, xp[c] * coef);
}

// ---------- layer-2 GEMM (bias1 fused) + attention coefs + state init ----------
__global__ __launch_bounds__(256) void gemm2_prep(const float* __restrict__ agg1,
                                                  const float* __restrict__ bias1,
                                                  const float* __restrict__ W2,
                                                  const float* __restrict__ att_src2,
                                                  const float* __restrict__ att_dst2,
                                                  float* __restrict__ xl2,
                                                  float* __restrict__ a_src2, float* __restrict__ a_dst2,
                                                  float* __restrict__ m2, float* __restrict__ d2,
                                                  float* __restrict__ agg2, int N) {
  __shared__ float hs[16 * 68];
  int tid = threadIdx.x;
  int n0 = blockIdx.x << 4;
  {
    int node = tid >> 4;
    int off = (tid & 15) << 2;
    int nn = n0 + node;
    float4 v = make_float4(0.f, 0.f, 0.f, 0.f);
    if (nn < N) {
      v = *(const float4*)(agg1 + (size_t)nn * 64 + off);
      float4 b = *(const float4*)(bias1 + off);
      v.x += b.x; v.y += b.y; v.z += b.z; v.w += b.w;
    }
    *(float4*)(hs + node * 68 + off) = v;
  }
  __syncthreads();
  int t = tid >> 4, c = tid & 15;
  int n = n0 + t;
  if (n >= N) return;
  float sum = 0.f;
#pragma unroll
  for (int k = 0; k < 64; ++k) sum += hs[t * 68 + k] * W2[k * 16 + c];
  xl2[(size_t)n * 16 + c] = sum;
  agg2[(size_t)n * 16 + c] = 0.f;
  float ps = sum * att_src2[c];
  float pd = sum * att_dst2[c];
#pragma unroll
  for (int w = 8; w >= 1; w >>= 1) {
    ps += __shfl_xor(ps, w, 16);
    pd += __shfl_xor(pd, w, 16);
  }
  if (c == 0) {
    a_src2[n] = ps;
    a_dst2[n] = pd;
    m2[n] = -INFINITY;
    d2[n] = 0.f;
  }
}

// ---------- layer-2 edge passes ----------
__global__ void edge2_max(const int* __restrict__ ei, int E, int N,
                          const float* __restrict__ a_src, const float* __restrict__ a_dst,
                          float* __restrict__ m2) {
  int e = blockIdx.x * blockDim.x + threadIdx.x;
  if (e >= E + N) return;
  int s, d;
  if (e < E) { s = ei[e]; d = ei[E + e]; } else { s = d = e - E; }
  float a = a_src[s] + a_dst[d];
  a = a >= 0.f ? a : NEG_SLOPE * a;
  atomicMaxF(m2 + d, a);
}

__global__ void edge2_sum(const int* __restrict__ ei, int E, int N,
                          const float* __restrict__ a_src, const float* __restrict__ a_dst,
                          const float* __restrict__ m2, float* __restrict__ d2) {
  int e = blockIdx.x * blockDim.x + threadIdx.x;
  if (e >= E + N) return;
  int s, d;
  if (e < E) { s = ei[e]; d = ei[E + e]; } else { s = d = e - E; }
  float a = a_src[s] + a_dst[d];
  a = a >= 0.f ? a : NEG_SLOPE * a;
  atomicAddF(d2 + d, __expf(a - m2[d]));
}

__global__ void edge2_agg(const int* __restrict__ ei, int E, int N,
                          const float* __restrict__ a_src, const float* __restrict__ a_dst,
                          const float* __restrict__ m2, const float* __restrict__ d2,
                          const float* __restrict__ xl2, float* __restrict__ agg2) {
  int e = blockIdx.x * blockDim.x + threadIdx.x;
  if (e >= E + N) return;
  int s, d;
  if (e < E) { s = ei[e]; d = ei[E + e]; } else { s = d = e - E; }
  float a = a_src[s] + a_dst[d];
  a = a >= 0.f ? a : NEG_SLOPE * a;
  float coef = __expf(a - m2[d]) / (d2[d] + 1e-16f);
  const float* xp = xl2 + (size_t)s * 16;
  float* op = agg2 + (size_t)d * 16;
#pragma unroll
  for (int c = 0; c < 16; ++c) atomicAddF(op + c, xp[c] * coef);
}

// ---------- bias2 + ELU + log_softmax ----------
__global__ void finalize_kernel(const float* __restrict__ agg2, const float* __restrict__ bias2,
                                float* __restrict__ out, int N) {
  int n = blockIdx.x * blockDim.x + threadIdx.x;
  if (n >= N) return;
  float v[16];
  float mx = -INFINITY;
#pragma unroll
  for (int c = 0; c < 16; ++c) {
    float o = agg2[(size_t)n * 16 + c] + bias2[c];
    o = o > 0.f ? o : expm1f(o);  // elu, alpha=1
    v[c] = o;
    mx = fmaxf(mx, o);
  }
  float ssum = 0.f;
#pragma unroll
  for (int c = 0; c < 16; ++c) ssum += __expf(v[c] - mx);
  float lse = mx + logf(ssum);
#pragma unroll
  for (int c = 0; c < 16; ++c) out[(size_t)n * 16 + c] = v[c] - lse;
}

extern "C" void kernel_launch(void* const* d_in, const int* in_sizes, int n_in,
                              void* d_out, int out_size, void* d_ws, size_t ws_size,
                              hipStream_t stream) {
  const float* x        = (const float*)d_in[0];
  const int*   ei       = (const int*)d_in[1];
  const float* W1       = (const float*)d_in[2];
  const float* att_src1 = (const float*)d_in[3];
  const float* att_dst1 = (const float*)d_in[4];
  const float* bias1    = (const float*)d_in[5];
  const float* W2       = (const float*)d_in[6];
  const float* att_src2 = (const float*)d_in[7];
  const float* att_dst2 = (const float*)d_in[8];
  const float* bias2    = (const float*)d_in[9];
  float* out = (float*)d_out;

  int N = in_sizes[0] / 512;
  int E = in_sizes[1] / 2;
  int EN = E + N;

  float* ws = (float*)d_ws;
  float* xl     = ws;                        // N*64
  float* a_src1 = xl + (size_t)N * 64;       // N*8
  float* a_dst1 = a_src1 + (size_t)N * 8;    // N*8
  float* m1     = a_dst1 + (size_t)N * 8;    // N*8
  float* d1     = m1 + (size_t)N * 8;        // N*8
  float* agg1   = d1 + (size_t)N * 8;        // N*64
  float* xl2    = agg1 + (size_t)N * 64;     // N*16
  float* a_src2 = xl2 + (size_t)N * 16;      // N
  float* a_dst2 = a_src2 + N;                // N
  float* m2     = a_dst2 + N;                // N
  float* d2     = m2 + N;                    // N
  float* agg2   = d2 + N;                    // N*16

  gemm1_kernel<<<(N + 63) / 64, 256, 0, stream>>>(x, W1, xl, N);
  node1_prep<<<(N * 8 + 255) / 256, 256, 0, stream>>>(xl, att_src1, att_dst1,
                                                      a_src1, a_dst1, m1, d1, agg1, N);
  edge1_max<<<(EN + 255) / 256, 256, 0, stream>>>(ei, E, N, a_src1, a_dst1, m1);
  edge1_sum<<<(EN + 255) / 256, 256, 0, stream>>>(ei, E, N, a_src1, a_dst1, m1, d1);
  edge1_agg<<<(EN * 8 + 255) / 256, 256, 0, stream>>>(ei, E, N, a_src1, a_dst1, m1, d1, xl, agg1);
  gemm2_prep<<<(N + 15) / 16, 256, 0, stream>>>(agg1, bias1, W2, att_src2, att_dst2,
                                                xl2, a_src2, a_dst2, m2, d2, agg2, N);
  edge2_max<<<(EN + 255) / 256, 256, 0, stream>>>(ei, E, N, a_src2, a_dst2, m2);
  edge2_sum<<<(EN + 255) / 256, 256, 0, stream>>>(ei, E, N, a_src2, a_dst2, m2, d2);
  edge2_agg<<<(EN + 255) / 256, 256, 0, stream>>>(ei, E, N, a_src2, a_dst2, m2, d2, xl2, agg2);
  finalize_kernel<<<(N + 255) / 256, 256, 0, stream>>>(agg2, bias2, out, N);
}

// Round 2
// 528.419 us; speedup vs baseline: 5.9316x; 5.9316x over previous
//
#include <hip/hip_runtime.h>
#include <math.h>

#define NEG_SLOPE 0.2f

// ---------- GEMM1: C[M,64] = A[M,512] @ B[512,64], fp32 ----------
__global__ __launch_bounds__(256) void gemm1_kernel(const float* __restrict__ A,
                                                    const float* __restrict__ B,
                                                    float* __restrict__ C, int M) {
  __shared__ float As[16][68];  // [kk][row], padded
  __shared__ float Bs[16][68];  // [kk][col], padded
  const int K = 512;
  int tid = threadIdx.x;
  int ty = tid >> 4, tx = tid & 15;
  int row0 = blockIdx.x << 6;
  float acc[4][4] = {};
  int la_row = tid >> 2;          // 0..63
  int la_k4  = (tid & 3) << 2;    // 0,4,8,12
  int lb_k   = tid >> 4;          // 0..15
  int lb_c4  = (tid & 15) << 2;   // 0..60
  for (int k0 = 0; k0 < K; k0 += 16) {
    float4 av = make_float4(0.f, 0.f, 0.f, 0.f);
    int ar = row0 + la_row;
    if (ar < M) av = *(const float4*)(A + (size_t)ar * K + k0 + la_k4);
    As[la_k4 + 0][la_row] = av.x;
    As[la_k4 + 1][la_row] = av.y;
    As[la_k4 + 2][la_row] = av.z;
    As[la_k4 + 3][la_row] = av.w;
    float4 bv = *(const float4*)(B + (size_t)(k0 + lb_k) * 64 + lb_c4);
    *(float4*)(&Bs[lb_k][lb_c4]) = bv;
    __syncthreads();
#pragma unroll
    for (int kk = 0; kk < 16; ++kk) {
      float4 a4 = *(const float4*)(&As[kk][ty << 2]);
      float4 b4 = *(const float4*)(&Bs[kk][tx << 2]);
      float a[4] = {a4.x, a4.y, a4.z, a4.w};
      float b[4] = {b4.x, b4.y, b4.z, b4.w};
#pragma unroll
      for (int i = 0; i < 4; ++i)
#pragma unroll
        for (int j = 0; j < 4; ++j)
          acc[i][j] += a[i] * b[j];
    }
    __syncthreads();
  }
#pragma unroll
  for (int i = 0; i < 4; ++i) {
    int r = row0 + (ty << 2) + i;
    if (r < M) {
      float4 o = make_float4(acc[i][0], acc[i][1], acc[i][2], acc[i][3]);
      *(float4*)(C + (size_t)r * 64 + (tx << 2)) = o;
    }
  }
}

// ---------- CSR build ----------
__global__ void deg_init(int* __restrict__ deg, int N) {
  int n = blockIdx.x * blockDim.x + threadIdx.x;
  if (n < N) deg[n] = 1;  // self-loop
}

__global__ void deg_hist(const int* __restrict__ ei, int* __restrict__ deg, int E) {
  int e = blockIdx.x * blockDim.x + threadIdx.x;
  if (e < E) atomicAdd(&deg[ei[E + e]], 1);
}

// single-block exclusive scan over deg[0..N) -> rowptr[0..N], cursor copy
__global__ __launch_bounds__(1024) void scan_kernel(const int* __restrict__ deg,
                                                    int* __restrict__ rowptr,
                                                    int* __restrict__ cursor, int N) {
  __shared__ int sums[1024];
  int tid = threadIdx.x;
  int chunk = (N + 1023) >> 10;
  int start = tid * chunk;
  int end = min(start + chunk, N);
  int s = 0;
  for (int i = start; i < end; ++i) s += deg[i];
  sums[tid] = s;
  __syncthreads();
  for (int off = 1; off < 1024; off <<= 1) {
    int t = (tid >= off) ? sums[tid - off] : 0;
    __syncthreads();
    sums[tid] += t;
    __syncthreads();
  }
  int run = (tid == 0) ? 0 : sums[tid - 1];
  for (int i = start; i < end; ++i) {
    rowptr[i] = run;
    cursor[i] = run;
    run += deg[i];
  }
  if (tid == 0) rowptr[N] = sums[1023];
}

__global__ void scatter_kernel(const int* __restrict__ ei, int* __restrict__ cursor,
                               int* __restrict__ srcs, int E, int N) {
  int i = blockIdx.x * blockDim.x + threadIdx.x;
  if (i >= E + N) return;
  int s, d;
  if (i < E) { s = ei[i]; d = ei[E + i]; } else { s = d = i - E; }
  int pos = atomicAdd(&cursor[d], 1);
  srcs[pos] = s;
}

// ---------- per-(node,head) attention coefs for layer 1 ----------
__global__ void node1_prep(const float* __restrict__ xl,
                           const float* __restrict__ att_src, const float* __restrict__ att_dst,
                           float* __restrict__ a_src, float* __restrict__ a_dst, int N) {
  int t = blockIdx.x * blockDim.x + threadIdx.x;
  if (t >= N * 8) return;
  int n = t >> 3, h = t & 7;
  const float* xp = xl + (size_t)n * 64 + h * 8;
  float s = 0.f, d = 0.f;
#pragma unroll
  for (int c = 0; c < 8; ++c) {
    float v = xp[c];
    s += v * att_src[h * 8 + c];
    d += v * att_dst[h * 8 + c];
  }
  a_src[t] = s;
  a_dst[t] = d;
}

// ---------- layer-1 aggregation: one 64-lane wave per dst node ----------
// lane c in [0,64): channel c, head h = c>>3. Online softmax state (m, den)
// is replicated (identical) across the 8 lanes of each head — no cross-lane ops.
__global__ __launch_bounds__(256) void agg1_csr(const int* __restrict__ rowptr,
                                                const int* __restrict__ srcs,
                                                const float* __restrict__ a_src,
                                                const float* __restrict__ a_dst,
                                                const float* __restrict__ xl,
                                                float* __restrict__ agg1, int N) {
  int wave = (blockIdx.x * blockDim.x + threadIdx.x) >> 6;
  int lane = threadIdx.x & 63;
  if (wave >= N) return;
  int h = lane >> 3;
  int beg = rowptr[wave], end = rowptr[wave + 1];
  float ad = a_dst[wave * 8 + h];
  float m = -INFINITY, den = 0.f, acc = 0.f;
  for (int p = beg; p < end; ++p) {
    int s = srcs[p];
    float a = a_src[s * 8 + h] + ad;
    a = a >= 0.f ? a : NEG_SLOPE * a;
    float newm = fmaxf(m, a);
    float scale = __expf(m - newm);
    float w = __expf(a - newm);
    den = den * scale + w;
    acc = acc * scale + w * xl[(size_t)s * 64 + lane];
    m = newm;
  }
  agg1[(size_t)wave * 64 + lane] = acc / (den + 1e-16f);
}

// ---------- layer-2 GEMM (bias1 fused) + attention coefs ----------
__global__ __launch_bounds__(256) void gemm2_prep(const float* __restrict__ agg1,
                                                  const float* __restrict__ bias1,
                                                  const float* __restrict__ W2,
                                                  const float* __restrict__ att_src2,
                                                  const float* __restrict__ att_dst2,
                                                  float* __restrict__ xl2,
                                                  float* __restrict__ a_src2,
                                                  float* __restrict__ a_dst2, int N) {
  __shared__ float hs[16 * 68];
  int tid = threadIdx.x;
  int n0 = blockIdx.x << 4;
  {
    int node = tid >> 4;
    int off = (tid & 15) << 2;
    int nn = n0 + node;
    float4 v = make_float4(0.f, 0.f, 0.f, 0.f);
    if (nn < N) {
      v = *(const float4*)(agg1 + (size_t)nn * 64 + off);
      float4 b = *(const float4*)(bias1 + off);
      v.x += b.x; v.y += b.y; v.z += b.z; v.w += b.w;
    }
    *(float4*)(hs + node * 68 + off) = v;
  }
  __syncthreads();
  int t = tid >> 4, c = tid & 15;
  int n = n0 + t;
  if (n >= N) return;
  float sum = 0.f;
#pragma unroll
  for (int k = 0; k < 64; ++k) sum += hs[t * 68 + k] * W2[k * 16 + c];
  xl2[(size_t)n * 16 + c] = sum;
  float ps = sum * att_src2[c];
  float pd = sum * att_dst2[c];
#pragma unroll
  for (int w = 8; w >= 1; w >>= 1) {
    ps += __shfl_xor(ps, w, 16);
    pd += __shfl_xor(pd, w, 16);
  }
  if (c == 0) {
    a_src2[n] = ps;
    a_dst2[n] = pd;
  }
}

// ---------- layer-2 aggregation + bias2 + ELU + log_softmax ----------
// 16 lanes per node (4 nodes per wave); lane = output class.
__global__ __launch_bounds__(256) void agg2_fin(const int* __restrict__ rowptr,
                                                const int* __restrict__ srcs,
                                                const float* __restrict__ a_src2,
                                                const float* __restrict__ a_dst2,
                                                const float* __restrict__ xl2,
                                                const float* __restrict__ bias2,
                                                float* __restrict__ out, int N) {
  int t = blockIdx.x * blockDim.x + threadIdx.x;
  int node = t >> 4;
  int c = t & 15;
  if (node >= N) return;
  int beg = rowptr[node], end = rowptr[node + 1];
  float ad = a_dst2[node];
  float m = -INFINITY, den = 0.f, acc = 0.f;
  for (int p = beg; p < end; ++p) {
    int s = srcs[p];
    float a = a_src2[s] + ad;
    a = a >= 0.f ? a : NEG_SLOPE * a;
    float newm = fmaxf(m, a);
    float scale = __expf(m - newm);
    float w = __expf(a - newm);
    den = den * scale + w;
    acc = acc * scale + w * xl2[(size_t)s * 16 + c];
    m = newm;
  }
  float o = acc / (den + 1e-16f) + bias2[c];
  o = o > 0.f ? o : expm1f(o);  // ELU alpha=1
  float mx = o;
#pragma unroll
  for (int w = 8; w >= 1; w >>= 1) mx = fmaxf(mx, __shfl_xor(mx, w, 16));
  float e = __expf(o - mx);
  float ssum = e;
#pragma unroll
  for (int w = 8; w >= 1; w >>= 1) ssum += __shfl_xor(ssum, w, 16);
  out[(size_t)node * 16 + c] = o - mx - logf(ssum);
}

extern "C" void kernel_launch(void* const* d_in, const int* in_sizes, int n_in,
                              void* d_out, int out_size, void* d_ws, size_t ws_size,
                              hipStream_t stream) {
  const float* x        = (const float*)d_in[0];
  const int*   ei       = (const int*)d_in[1];
  const float* W1       = (const float*)d_in[2];
  const float* att_src1 = (const float*)d_in[3];
  const float* att_dst1 = (const float*)d_in[4];
  const float* bias1    = (const float*)d_in[5];
  const float* W2       = (const float*)d_in[6];
  const float* att_src2 = (const float*)d_in[7];
  const float* att_dst2 = (const float*)d_in[8];
  const float* bias2    = (const float*)d_in[9];
  float* out = (float*)d_out;

  int N = in_sizes[0] / 512;
  int E = in_sizes[1] / 2;

  char* ws = (char*)d_ws;
  float* xl     = (float*)ws;                       ws += (size_t)N * 64 * 4;
  float* a_src1 = (float*)ws;                       ws += (size_t)N * 8 * 4;
  float* a_dst1 = (float*)ws;                       ws += (size_t)N * 8 * 4;
  float* agg1   = (float*)ws;                       ws += (size_t)N * 64 * 4;
  float* xl2    = (float*)ws;                       ws += (size_t)N * 16 * 4;
  float* a_src2 = (float*)ws;                       ws += (size_t)N * 4;
  float* a_dst2 = (float*)ws;                       ws += (size_t)N * 4;
  int* deg      = (int*)ws;                         ws += (size_t)N * 4;
  int* rowptr   = (int*)ws;                         ws += (size_t)(N + 1) * 4;
  int* cursor   = (int*)ws;                         ws += (size_t)N * 4;
  int* srcs     = (int*)ws;                         ws += (size_t)(E + N) * 4;

  // CSR build (by destination), self-loops included via deg init = 1
  deg_init<<<(N + 255) / 256, 256, 0, stream>>>(deg, N);
  deg_hist<<<(E + 255) / 256, 256, 0, stream>>>(ei, deg, E);
  scan_kernel<<<1, 1024, 0, stream>>>(deg, rowptr, cursor, N);
  scatter_kernel<<<(E + N + 255) / 256, 256, 0, stream>>>(ei, cursor, srcs, E, N);

  // layer 1
  gemm1_kernel<<<(N + 63) / 64, 256, 0, stream>>>(x, W1, xl, N);
  node1_prep<<<(N * 8 + 255) / 256, 256, 0, stream>>>(xl, att_src1, att_dst1, a_src1, a_dst1, N);
  agg1_csr<<<((size_t)N * 64 + 255) / 256, 256, 0, stream>>>(rowptr, srcs, a_src1, a_dst1, xl, agg1, N);

  // layer 2
  gemm2_prep<<<(N + 15) / 16, 256, 0, stream>>>(agg1, bias1, W2, att_src2, att_dst2,
                                                xl2, a_src2, a_dst2, N);
  agg2_fin<<<((size_t)N * 16 + 255) / 256, 256, 0, stream>>>(rowptr, srcs, a_src2, a_dst2,
                                                             xl2, bias2, out, N);
}

// Round 3
// 430.023 us; speedup vs baseline: 7.2889x; 1.2288x over previous
//
#include <hip/hip_runtime.h>
#include <math.h>

#define NEG_SLOPE 0.2f

// ---------- GEMM1: C[M,64] = A[M,512] @ B[512,64], fp32 ----------
__global__ __launch_bounds__(256) void gemm1_kernel(const float* __restrict__ A,
                                                    const float* __restrict__ B,
                                                    float* __restrict__ C, int M) {
  __shared__ float As[16][68];  // [kk][row], padded
  __shared__ float Bs[16][68];  // [kk][col], padded
  const int K = 512;
  int tid = threadIdx.x;
  int ty = tid >> 4, tx = tid & 15;
  int row0 = blockIdx.x << 6;
  float acc[4][4] = {};
  int la_row = tid >> 2;          // 0..63
  int la_k4  = (tid & 3) << 2;    // 0,4,8,12
  int lb_k   = tid >> 4;          // 0..15
  int lb_c4  = (tid & 15) << 2;   // 0..60
  for (int k0 = 0; k0 < K; k0 += 16) {
    float4 av = make_float4(0.f, 0.f, 0.f, 0.f);
    int ar = row0 + la_row;
    if (ar < M) av = *(const float4*)(A + (size_t)ar * K + k0 + la_k4);
    As[la_k4 + 0][la_row] = av.x;
    As[la_k4 + 1][la_row] = av.y;
    As[la_k4 + 2][la_row] = av.z;
    As[la_k4 + 3][la_row] = av.w;
    float4 bv = *(const float4*)(B + (size_t)(k0 + lb_k) * 64 + lb_c4);
    *(float4*)(&Bs[lb_k][lb_c4]) = bv;
    __syncthreads();
#pragma unroll
    for (int kk = 0; kk < 16; ++kk) {
      float4 a4 = *(const float4*)(&As[kk][ty << 2]);
      float4 b4 = *(const float4*)(&Bs[kk][tx << 2]);
      float a[4] = {a4.x, a4.y, a4.z, a4.w};
      float b[4] = {b4.x, b4.y, b4.z, b4.w};
#pragma unroll
      for (int i = 0; i < 4; ++i)
#pragma unroll
        for (int j = 0; j < 4; ++j)
          acc[i][j] += a[i] * b[j];
    }
    __syncthreads();
  }
#pragma unroll
  for (int i = 0; i < 4; ++i) {
    int r = row0 + (ty << 2) + i;
    if (r < M) {
      float4 o = make_float4(acc[i][0], acc[i][1], acc[i][2], acc[i][3]);
      *(float4*)(C + (size_t)r * 64 + (tx << 2)) = o;
    }
  }
}

// ---------- CSR build ----------
__global__ void deg_init(int* __restrict__ deg, int N) {
  int n = blockIdx.x * blockDim.x + threadIdx.x;
  if (n < N) deg[n] = 1;  // self-loop
}

__global__ void deg_hist(const int* __restrict__ ei, int* __restrict__ deg, int E) {
  int e = blockIdx.x * blockDim.x + threadIdx.x;
  if (e < E) atomicAdd(&deg[ei[E + e]], 1);
}

// hierarchical scan, chunk = 512 elements per 256-thread block
__global__ __launch_bounds__(256) void partial_sums(const int* __restrict__ deg,
                                                    int* __restrict__ partials, int N) {
  __shared__ int ws[4];
  int base = blockIdx.x * 512;
  int tid = threadIdx.x;
  int i0 = base + tid * 2;
  int s = 0;
  if (i0 < N) s += deg[i0];
  if (i0 + 1 < N) s += deg[i0 + 1];
#pragma unroll
  for (int off = 32; off >= 1; off >>= 1) s += __shfl_xor(s, off, 64);
  if ((tid & 63) == 0) ws[tid >> 6] = s;
  __syncthreads();
  if (tid == 0) partials[blockIdx.x] = ws[0] + ws[1] + ws[2] + ws[3];
}

__global__ __launch_bounds__(256) void scan_partials(const int* __restrict__ partials,
                                                     int* __restrict__ blockoff,
                                                     int* __restrict__ rowptr, int nb, int N) {
  __shared__ int sums[256];
  int tid = threadIdx.x;
  int chunk = (nb + 255) >> 8;
  int start = tid * chunk, end = min(start + chunk, nb);
  int s = 0;
  for (int i = start; i < end; ++i) s += partials[i];
  sums[tid] = s;
  __syncthreads();
  for (int off = 1; off < 256; off <<= 1) {
    int t = (tid >= off) ? sums[tid - off] : 0;
    __syncthreads();
    sums[tid] += t;
    __syncthreads();
  }
  int run = (tid == 0) ? 0 : sums[tid - 1];
  for (int i = start; i < end; ++i) {
    blockoff[i] = run;
    run += partials[i];
  }
  if (tid == 255) rowptr[N] = sums[255];
}

__global__ __launch_bounds__(256) void scan_blocks(const int* __restrict__ deg,
                                                   const int* __restrict__ blockoff,
                                                   int* __restrict__ rowptr,
                                                   int* __restrict__ cursor, int N) {
  __shared__ int wavesum[4];
  int base = blockIdx.x * 512;
  int tid = threadIdx.x;
  int lane = tid & 63, wv = tid >> 6;
  int i0 = base + tid * 2;
  int d0 = (i0 < N) ? deg[i0] : 0;
  int d1 = (i0 + 1 < N) ? deg[i0 + 1] : 0;
  int s = d0 + d1;
  int v = s;
#pragma unroll
  for (int off = 1; off < 64; off <<= 1) {
    int t = __shfl_up(v, off, 64);
    if (lane >= off) v += t;
  }
  if (lane == 63) wavesum[wv] = v;
  __syncthreads();
  int woff = 0;
  for (int w = 0; w < wv; ++w) woff += wavesum[w];
  int excl = v - s + woff + blockoff[blockIdx.x];
  if (i0 < N) { rowptr[i0] = excl; cursor[i0] = excl; }
  if (i0 + 1 < N) { rowptr[i0 + 1] = excl + d0; cursor[i0 + 1] = excl + d0; }
}

__global__ void scatter_kernel(const int* __restrict__ ei, int* __restrict__ cursor,
                               int* __restrict__ srcs, int E, int N) {
  int i = blockIdx.x * blockDim.x + threadIdx.x;
  if (i >= E + N) return;
  int s, d;
  if (i < E) { s = ei[i]; d = ei[E + i]; } else { s = d = i - E; }
  int pos = atomicAdd(&cursor[d], 1);
  srcs[pos] = s;
}

// ---------- per-(node,head) attention coefs for layer 1 ----------
__global__ void node1_prep(const float* __restrict__ xl,
                           const float* __restrict__ att_src, const float* __restrict__ att_dst,
                           float* __restrict__ a_src, float* __restrict__ a_dst, int N) {
  int t = blockIdx.x * blockDim.x + threadIdx.x;
  if (t >= N * 8) return;
  int n = t >> 3, h = t & 7;
  const float* xp = xl + (size_t)n * 64 + h * 8;
  float s = 0.f, d = 0.f;
#pragma unroll
  for (int c = 0; c < 8; ++c) {
    float v = xp[c];
    s += v * att_src[h * 8 + c];
    d += v * att_dst[h * 8 + c];
  }
  a_src[t] = s;
  a_dst[t] = d;
}

// ---------- layer-1 aggregation: one 64-lane wave per dst node ----------
__global__ __launch_bounds__(256) void agg1_csr(const int* __restrict__ rowptr,
                                                const int* __restrict__ srcs,
                                                const float* __restrict__ a_src,
                                                const float* __restrict__ a_dst,
                                                const float* __restrict__ xl,
                                                float* __restrict__ agg1, int N) {
  int wave = (blockIdx.x * blockDim.x + threadIdx.x) >> 6;
  int lane = threadIdx.x & 63;
  if (wave >= N) return;
  int h = lane >> 3;
  int beg = rowptr[wave], end = rowptr[wave + 1];
  float ad = a_dst[wave * 8 + h];
  float m = -INFINITY, den = 0.f, acc = 0.f;
  for (int p = beg; p < end; ++p) {
    int s = srcs[p];
    float a = a_src[s * 8 + h] + ad;
    a = a >= 0.f ? a : NEG_SLOPE * a;
    float newm = fmaxf(m, a);
    float scale = __expf(m - newm);
    float w = __expf(a - newm);
    den = den * scale + w;
    acc = acc * scale + w * xl[(size_t)s * 64 + lane];
    m = newm;
  }
  agg1[(size_t)wave * 64 + lane] = acc / (den + 1e-16f);
}

// ---------- layer-2 GEMM (bias1 fused) + attention coefs ----------
__global__ __launch_bounds__(256) void gemm2_prep(const float* __restrict__ agg1,
                                                  const float* __restrict__ bias1,
                                                  const float* __restrict__ W2,
                                                  const float* __restrict__ att_src2,
                                                  const float* __restrict__ att_dst2,
                                                  float* __restrict__ xl2,
                                                  float* __restrict__ a_src2,
                                                  float* __restrict__ a_dst2, int N) {
  __shared__ float hs[16 * 68];
  int tid = threadIdx.x;
  int n0 = blockIdx.x << 4;
  {
    int node = tid >> 4;
    int off = (tid & 15) << 2;
    int nn = n0 + node;
    float4 v = make_float4(0.f, 0.f, 0.f, 0.f);
    if (nn < N) {
      v = *(const float4*)(agg1 + (size_t)nn * 64 + off);
      float4 b = *(const float4*)(bias1 + off);
      v.x += b.x; v.y += b.y; v.z += b.z; v.w += b.w;
    }
    *(float4*)(hs + node * 68 + off) = v;
  }
  __syncthreads();
  int t = tid >> 4, c = tid & 15;
  int n = n0 + t;
  if (n >= N) return;
  float sum = 0.f;
#pragma unroll
  for (int k = 0; k < 64; ++k) sum += hs[t * 68 + k] * W2[k * 16 + c];
  xl2[(size_t)n * 16 + c] = sum;
  float ps = sum * att_src2[c];
  float pd = sum * att_dst2[c];
#pragma unroll
  for (int w = 8; w >= 1; w >>= 1) {
    ps += __shfl_xor(ps, w, 16);
    pd += __shfl_xor(pd, w, 16);
  }
  if (c == 0) {
    a_src2[n] = ps;
    a_dst2[n] = pd;
  }
}

// ---------- layer-2 aggregation + bias2 + ELU + log_softmax ----------
__global__ __launch_bounds__(256) void agg2_fin(const int* __restrict__ rowptr,
                                                const int* __restrict__ srcs,
                                                const float* __restrict__ a_src2,
                                                const float* __restrict__ a_dst2,
                                                const float* __restrict__ xl2,
                                                const float* __restrict__ bias2,
                                                float* __restrict__ out, int N) {
  int t = blockIdx.x * blockDim.x + threadIdx.x;
  int node = t >> 4;
  int c = t & 15;
  if (node >= N) return;
  int beg = rowptr[node], end = rowptr[node + 1];
  float ad = a_dst2[node];
  float m = -INFINITY, den = 0.f, acc = 0.f;
  for (int p = beg; p < end; ++p) {
    int s = srcs[p];
    float a = a_src2[s] + ad;
    a = a >= 0.f ? a : NEG_SLOPE * a;
    float newm = fmaxf(m, a);
    float scale = __expf(m - newm);
    float w = __expf(a - newm);
    den = den * scale + w;
    acc = acc * scale + w * xl2[(size_t)s * 16 + c];
    m = newm;
  }
  float o = acc / (den + 1e-16f) + bias2[c];
  o = o > 0.f ? o : expm1f(o);  // ELU alpha=1
  float mx = o;
#pragma unroll
  for (int w = 8; w >= 1; w >>= 1) mx = fmaxf(mx, __shfl_xor(mx, w, 16));
  float e = __expf(o - mx);
  float ssum = e;
#pragma unroll
  for (int w = 8; w >= 1; w >>= 1) ssum += __shfl_xor(ssum, w, 16);
  out[(size_t)node * 16 + c] = o - mx - logf(ssum);
}

extern "C" void kernel_launch(void* const* d_in, const int* in_sizes, int n_in,
                              void* d_out, int out_size, void* d_ws, size_t ws_size,
                              hipStream_t stream) {
  const float* x        = (const float*)d_in[0];
  const int*   ei       = (const int*)d_in[1];
  const float* W1       = (const float*)d_in[2];
  const float* att_src1 = (const float*)d_in[3];
  const float* att_dst1 = (const float*)d_in[4];
  const float* bias1    = (const float*)d_in[5];
  const float* W2       = (const float*)d_in[6];
  const float* att_src2 = (const float*)d_in[7];
  const float* att_dst2 = (const float*)d_in[8];
  const float* bias2    = (const float*)d_in[9];
  float* out = (float*)d_out;

  int N = in_sizes[0] / 512;
  int E = in_sizes[1] / 2;
  int nb = (N + 511) / 512;

  char* ws = (char*)d_ws;
  float* xl     = (float*)ws;                       ws += (size_t)N * 64 * 4;
  float* a_src1 = (float*)ws;                       ws += (size_t)N * 8 * 4;
  float* a_dst1 = (float*)ws;                       ws += (size_t)N * 8 * 4;
  float* agg1   = (float*)ws;                       ws += (size_t)N * 64 * 4;
  float* xl2    = (float*)ws;                       ws += (size_t)N * 16 * 4;
  float* a_src2 = (float*)ws;                       ws += (size_t)N * 4;
  float* a_dst2 = (float*)ws;                       ws += (size_t)N * 4;
  int* deg      = (int*)ws;                         ws += (size_t)N * 4;
  int* rowptr   = (int*)ws;                         ws += (size_t)(N + 1) * 4;
  int* cursor   = (int*)ws;                         ws += (size_t)N * 4;
  int* srcs     = (int*)ws;                         ws += (size_t)(E + N) * 4;
  int* partials = (int*)ws;                         ws += (size_t)nb * 4;
  int* blockoff = (int*)ws;                         ws += (size_t)nb * 4;

  // CSR build (by destination), self-loops included via deg init = 1
  deg_init<<<(N + 255) / 256, 256, 0, stream>>>(deg, N);
  deg_hist<<<(E + 255) / 256, 256, 0, stream>>>(ei, deg, E);
  partial_sums<<<nb, 256, 0, stream>>>(deg, partials, N);
  scan_partials<<<1, 256, 0, stream>>>(partials, blockoff, rowptr, nb, N);
  scan_blocks<<<nb, 256, 0, stream>>>(deg, blockoff, rowptr, cursor, N);
  scatter_kernel<<<(E + N + 255) / 256, 256, 0, stream>>>(ei, cursor, srcs, E, N);

  // layer 1
  gemm1_kernel<<<(N + 63) / 64, 256, 0, stream>>>(x, W1, xl, N);
  node1_prep<<<(N * 8 + 255) / 256, 256, 0, stream>>>(xl, att_src1, att_dst1, a_src1, a_dst1, N);
  agg1_csr<<<((size_t)N * 64 + 255) / 256, 256, 0, stream>>>(rowptr, srcs, a_src1, a_dst1, xl, agg1, N);

  // layer 2
  gemm2_prep<<<(N + 15) / 16, 256, 0, stream>>>(agg1, bias1, W2, att_src2, att_dst2,
                                                xl2, a_src2, a_dst2, N);
  agg2_fin<<<((size_t)N * 16 + 255) / 256, 256, 0, stream>>>(rowptr, srcs, a_src2, a_dst2,
                                                             xl2, bias2, out, N);
}

// Round 4
// 354.931 us; speedup vs baseline: 8.8309x; 1.2116x over previous
//
#include <hip/hip_runtime.h>
#include <math.h>

#define NEG_SLOPE 0.2f

static __device__ __forceinline__ float bf2f(unsigned short u) {
  return __uint_as_float(((unsigned int)u) << 16);
}
static __device__ __forceinline__ unsigned short f2bf(float f) {
  unsigned int u = __float_as_uint(f);
  u = (u + 0x7fffu + ((u >> 16) & 1u)) >> 16;  // RNE
  return (unsigned short)u;
}

// ---------- GEMM1: xl_bf16[M,64] = A[M,512] @ B[512,64]; fused att coefs ----------
__global__ __launch_bounds__(256) void gemm1_kernel(const float* __restrict__ A,
                                                    const float* __restrict__ B,
                                                    const float* __restrict__ att_src,
                                                    const float* __restrict__ att_dst,
                                                    unsigned short* __restrict__ xlb,
                                                    float* __restrict__ a_src,
                                                    float* __restrict__ a_dst, int M) {
  __shared__ float As[16][68];  // [kk][row], padded
  __shared__ float Bs[16][68];  // [kk][col], padded
  const int K = 512;
  int tid = threadIdx.x;
  int ty = tid >> 4, tx = tid & 15;
  int row0 = blockIdx.x << 6;
  float acc[4][4] = {};
  int la_row = tid >> 2;          // 0..63
  int la_k4  = (tid & 3) << 2;    // 0,4,8,12
  int lb_k   = tid >> 4;          // 0..15
  int lb_c4  = (tid & 15) << 2;   // 0..60
  for (int k0 = 0; k0 < K; k0 += 16) {
    float4 av = make_float4(0.f, 0.f, 0.f, 0.f);
    int ar = row0 + la_row;
    if (ar < M) av = *(const float4*)(A + (size_t)ar * K + k0 + la_k4);
    As[la_k4 + 0][la_row] = av.x;
    As[la_k4 + 1][la_row] = av.y;
    As[la_k4 + 2][la_row] = av.z;
    As[la_k4 + 3][la_row] = av.w;
    float4 bv = *(const float4*)(B + (size_t)(k0 + lb_k) * 64 + lb_c4);
    *(float4*)(&Bs[lb_k][lb_c4]) = bv;
    __syncthreads();
#pragma unroll
    for (int kk = 0; kk < 16; ++kk) {
      float4 a4 = *(const float4*)(&As[kk][ty << 2]);
      float4 b4 = *(const float4*)(&Bs[kk][tx << 2]);
      float a[4] = {a4.x, a4.y, a4.z, a4.w};
      float b[4] = {b4.x, b4.y, b4.z, b4.w};
#pragma unroll
      for (int i = 0; i < 4; ++i)
#pragma unroll
        for (int j = 0; j < 4; ++j)
          acc[i][j] += a[i] * b[j];
    }
    __syncthreads();
  }
  // epilogue: bf16 store + per-head attention coefs
  int hh = tx >> 1;            // head for this thread's 4 cols (uniform)
  int c0 = (tx & 1) * 4;       // col offset within head
  float as0 = att_src[hh * 8 + c0 + 0], as1 = att_src[hh * 8 + c0 + 1];
  float as2 = att_src[hh * 8 + c0 + 2], as3 = att_src[hh * 8 + c0 + 3];
  float ad0 = att_dst[hh * 8 + c0 + 0], ad1 = att_dst[hh * 8 + c0 + 1];
  float ad2 = att_dst[hh * 8 + c0 + 2], ad3 = att_dst[hh * 8 + c0 + 3];
#pragma unroll
  for (int i = 0; i < 4; ++i) {
    int r = row0 + (ty << 2) + i;
    float sp = acc[i][0] * as0 + acc[i][1] * as1 + acc[i][2] * as2 + acc[i][3] * as3;
    float dp = acc[i][0] * ad0 + acc[i][1] * ad1 + acc[i][2] * ad2 + acc[i][3] * ad3;
    sp += __shfl_xor(sp, 1, 64);
    dp += __shfl_xor(dp, 1, 64);
    if (r < M) {
      ushort4 hv;
      hv.x = f2bf(acc[i][0]); hv.y = f2bf(acc[i][1]);
      hv.z = f2bf(acc[i][2]); hv.w = f2bf(acc[i][3]);
      *(ushort4*)(xlb + (size_t)r * 64 + (tx << 2)) = hv;
      if ((tx & 1) == 0) {
        a_src[r * 8 + hh] = sp;
        a_dst[r * 8 + hh] = dp;
      }
    }
  }
}

// ---------- CSR build ----------
__global__ void deg_init(int* __restrict__ deg, int N) {
  int n = blockIdx.x * blockDim.x + threadIdx.x;
  if (n < N) deg[n] = 1;  // self-loop
}

__global__ void deg_hist(const int* __restrict__ ei, int* __restrict__ deg, int E) {
  int e = blockIdx.x * blockDim.x + threadIdx.x;
  if (e < E) atomicAdd(&deg[ei[E + e]], 1);
}

// hierarchical scan, chunk = 512 elements per 256-thread block
__global__ __launch_bounds__(256) void partial_sums(const int* __restrict__ deg,
                                                    int* __restrict__ partials, int N) {
  __shared__ int ws[4];
  int base = blockIdx.x * 512;
  int tid = threadIdx.x;
  int i0 = base + tid * 2;
  int s = 0;
  if (i0 < N) s += deg[i0];
  if (i0 + 1 < N) s += deg[i0 + 1];
#pragma unroll
  for (int off = 32; off >= 1; off >>= 1) s += __shfl_xor(s, off, 64);
  if ((tid & 63) == 0) ws[tid >> 6] = s;
  __syncthreads();
  if (tid == 0) partials[blockIdx.x] = ws[0] + ws[1] + ws[2] + ws[3];
}

__global__ __launch_bounds__(256) void scan_partials(const int* __restrict__ partials,
                                                     int* __restrict__ blockoff,
                                                     int* __restrict__ rowptr, int nb, int N) {
  __shared__ int sums[256];
  int tid = threadIdx.x;
  int chunk = (nb + 255) >> 8;
  int start = tid * chunk, end = min(start + chunk, nb);
  int s = 0;
  for (int i = start; i < end; ++i) s += partials[i];
  sums[tid] = s;
  __syncthreads();
  for (int off = 1; off < 256; off <<= 1) {
    int t = (tid >= off) ? sums[tid - off] : 0;
    __syncthreads();
    sums[tid] += t;
    __syncthreads();
  }
  int run = (tid == 0) ? 0 : sums[tid - 1];
  for (int i = start; i < end; ++i) {
    blockoff[i] = run;
    run += partials[i];
  }
  if (tid == 255) rowptr[N] = sums[255];
}

__global__ __launch_bounds__(256) void scan_blocks(const int* __restrict__ deg,
                                                   const int* __restrict__ blockoff,
                                                   int* __restrict__ rowptr,
                                                   int* __restrict__ cursor, int N) {
  __shared__ int wavesum[4];
  int base = blockIdx.x * 512;
  int tid = threadIdx.x;
  int lane = tid & 63, wv = tid >> 6;
  int i0 = base + tid * 2;
  int d0 = (i0 < N) ? deg[i0] : 0;
  int d1 = (i0 + 1 < N) ? deg[i0 + 1] : 0;
  int s = d0 + d1;
  int v = s;
#pragma unroll
  for (int off = 1; off < 64; off <<= 1) {
    int t = __shfl_up(v, off, 64);
    if (lane >= off) v += t;
  }
  if (lane == 63) wavesum[wv] = v;
  __syncthreads();
  int woff = 0;
  for (int w = 0; w < wv; ++w) woff += wavesum[w];
  int excl = v - s + woff + blockoff[blockIdx.x];
  if (i0 < N) { rowptr[i0] = excl; cursor[i0] = excl; }
  if (i0 + 1 < N) { rowptr[i0 + 1] = excl + d0; cursor[i0 + 1] = excl + d0; }
}

__global__ void scatter_kernel(const int* __restrict__ ei, int* __restrict__ cursor,
                               int* __restrict__ srcs, int E, int N) {
  int i = blockIdx.x * blockDim.x + threadIdx.x;
  if (i >= E + N) return;
  int s, d;
  if (i < E) { s = ei[i]; d = ei[E + i]; } else { s = d = i - E; }
  int pos = atomicAdd(&cursor[d], 1);
  srcs[pos] = s;
}

// ---------- layer-1 aggregation: one 64-lane wave per dst node ----------
// lane = channel, head = lane>>3. No online max (softmax shift-invariant,
// |a| bounded ~2); unroll-4 for memory-level parallelism.
__global__ __launch_bounds__(256) void agg1_csr(const int* __restrict__ rowptr,
                                                const int* __restrict__ srcs,
                                                const float* __restrict__ a_src,
                                                const float* __restrict__ a_dst,
                                                const unsigned short* __restrict__ xlb,
                                                float* __restrict__ agg1, int N) {
  int wave = (blockIdx.x * blockDim.x + threadIdx.x) >> 6;
  int lane = threadIdx.x & 63;
  if (wave >= N) return;
  int h = lane >> 3;
  int beg = rowptr[wave], end = rowptr[wave + 1];
  float ad = a_dst[wave * 8 + h];
  float den = 0.f, acc = 0.f;
  int p = beg;
  for (; p + 4 <= end; p += 4) {
    int s0 = srcs[p], s1 = srcs[p + 1], s2 = srcs[p + 2], s3 = srcs[p + 3];
    float a0 = a_src[s0 * 8 + h], a1 = a_src[s1 * 8 + h];
    float a2 = a_src[s2 * 8 + h], a3 = a_src[s3 * 8 + h];
    float x0 = bf2f(xlb[(size_t)s0 * 64 + lane]);
    float x1 = bf2f(xlb[(size_t)s1 * 64 + lane]);
    float x2 = bf2f(xlb[(size_t)s2 * 64 + lane]);
    float x3 = bf2f(xlb[(size_t)s3 * 64 + lane]);
    a0 += ad; a1 += ad; a2 += ad; a3 += ad;
    a0 = a0 >= 0.f ? a0 : NEG_SLOPE * a0;
    a1 = a1 >= 0.f ? a1 : NEG_SLOPE * a1;
    a2 = a2 >= 0.f ? a2 : NEG_SLOPE * a2;
    a3 = a3 >= 0.f ? a3 : NEG_SLOPE * a3;
    float w0 = __expf(a0), w1 = __expf(a1), w2 = __expf(a2), w3 = __expf(a3);
    den += (w0 + w1) + (w2 + w3);
    acc += w0 * x0 + w1 * x1 + w2 * x2 + w3 * x3;
  }
  for (; p < end; ++p) {
    int s = srcs[p];
    float a = a_src[s * 8 + h] + ad;
    a = a >= 0.f ? a : NEG_SLOPE * a;
    float w = __expf(a);
    den += w;
    acc += w * bf2f(xlb[(size_t)s * 64 + lane]);
  }
  agg1[(size_t)wave * 64 + lane] = acc / (den + 1e-16f);
}

// ---------- layer-2 GEMM (bias1 fused) + attention coefs ----------
__global__ __launch_bounds__(256) void gemm2_prep(const float* __restrict__ agg1,
                                                  const float* __restrict__ bias1,
                                                  const float* __restrict__ W2,
                                                  const float* __restrict__ att_src2,
                                                  const float* __restrict__ att_dst2,
                                                  float* __restrict__ xl2,
                                                  float* __restrict__ a_src2,
                                                  float* __restrict__ a_dst2, int N) {
  __shared__ float hs[16 * 68];
  int tid = threadIdx.x;
  int n0 = blockIdx.x << 4;
  {
    int node = tid >> 4;
    int off = (tid & 15) << 2;
    int nn = n0 + node;
    float4 v = make_float4(0.f, 0.f, 0.f, 0.f);
    if (nn < N) {
      v = *(const float4*)(agg1 + (size_t)nn * 64 + off);
      float4 b = *(const float4*)(bias1 + off);
      v.x += b.x; v.y += b.y; v.z += b.z; v.w += b.w;
    }
    *(float4*)(hs + node * 68 + off) = v;
  }
  __syncthreads();
  int t = tid >> 4, c = tid & 15;
  int n = n0 + t;
  if (n >= N) return;
  float sum = 0.f;
#pragma unroll
  for (int k = 0; k < 64; ++k) sum += hs[t * 68 + k] * W2[k * 16 + c];
  xl2[(size_t)n * 16 + c] = sum;
  float ps = sum * att_src2[c];
  float pd = sum * att_dst2[c];
#pragma unroll
  for (int w = 8; w >= 1; w >>= 1) {
    ps += __shfl_xor(ps, w, 16);
    pd += __shfl_xor(pd, w, 16);
  }
  if (c == 0) {
    a_src2[n] = ps;
    a_dst2[n] = pd;
  }
}

// ---------- layer-2 aggregation + bias2 + ELU + log_softmax ----------
// 16 lanes per node (4 nodes per wave); lane = output class. No online max.
__global__ __launch_bounds__(256) void agg2_fin(const int* __restrict__ rowptr,
                                                const int* __restrict__ srcs,
                                                const float* __restrict__ a_src2,
                                                const float* __restrict__ a_dst2,
                                                const float* __restrict__ xl2,
                                                const float* __restrict__ bias2,
                                                float* __restrict__ out, int N) {
  int t = blockIdx.x * blockDim.x + threadIdx.x;
  int node = t >> 4;
  int c = t & 15;
  if (node >= N) return;
  int beg = rowptr[node], end = rowptr[node + 1];
  float ad = a_dst2[node];
  float den = 0.f, acc = 0.f;
  int p = beg;
  for (; p + 4 <= end; p += 4) {
    int s0 = srcs[p], s1 = srcs[p + 1], s2 = srcs[p + 2], s3 = srcs[p + 3];
    float a0 = a_src2[s0], a1 = a_src2[s1], a2 = a_src2[s2], a3 = a_src2[s3];
    float x0 = xl2[(size_t)s0 * 16 + c], x1 = xl2[(size_t)s1 * 16 + c];
    float x2 = xl2[(size_t)s2 * 16 + c], x3 = xl2[(size_t)s3 * 16 + c];
    a0 += ad; a1 += ad; a2 += ad; a3 += ad;
    a0 = a0 >= 0.f ? a0 : NEG_SLOPE * a0;
    a1 = a1 >= 0.f ? a1 : NEG_SLOPE * a1;
    a2 = a2 >= 0.f ? a2 : NEG_SLOPE * a2;
    a3 = a3 >= 0.f ? a3 : NEG_SLOPE * a3;
    float w0 = __expf(a0), w1 = __expf(a1), w2 = __expf(a2), w3 = __expf(a3);
    den += (w0 + w1) + (w2 + w3);
    acc += w0 * x0 + w1 * x1 + w2 * x2 + w3 * x3;
  }
  for (; p < end; ++p) {
    int s = srcs[p];
    float a = a_src2[s] + ad;
    a = a >= 0.f ? a : NEG_SLOPE * a;
    float w = __expf(a);
    den += w;
    acc += w * xl2[(size_t)s * 16 + c];
  }
  float o = acc / (den + 1e-16f) + bias2[c];
  o = o > 0.f ? o : expm1f(o);  // ELU alpha=1
  float mx = o;
#pragma unroll
  for (int w = 8; w >= 1; w >>= 1) mx = fmaxf(mx, __shfl_xor(mx, w, 16));
  float e = __expf(o - mx);
  float ssum = e;
#pragma unroll
  for (int w = 8; w >= 1; w >>= 1) ssum += __shfl_xor(ssum, w, 16);
  out[(size_t)node * 16 + c] = o - mx - logf(ssum);
}

extern "C" void kernel_launch(void* const* d_in, const int* in_sizes, int n_in,
                              void* d_out, int out_size, void* d_ws, size_t ws_size,
                              hipStream_t stream) {
  const float* x        = (const float*)d_in[0];
  const int*   ei       = (const int*)d_in[1];
  const float* W1       = (const float*)d_in[2];
  const float* att_src1 = (const float*)d_in[3];
  const float* att_dst1 = (const float*)d_in[4];
  const float* bias1    = (const float*)d_in[5];
  const float* W2       = (const float*)d_in[6];
  const float* att_src2 = (const float*)d_in[7];
  const float* att_dst2 = (const float*)d_in[8];
  const float* bias2    = (const float*)d_in[9];
  float* out = (float*)d_out;

  int N = in_sizes[0] / 512;
  int E = in_sizes[1] / 2;
  int nb = (N + 511) / 512;

  char* ws = (char*)d_ws;
  unsigned short* xlb = (unsigned short*)ws;        ws += (size_t)N * 64 * 2;
  float* a_src1 = (float*)ws;                       ws += (size_t)N * 8 * 4;
  float* a_dst1 = (float*)ws;                       ws += (size_t)N * 8 * 4;
  float* agg1   = (float*)ws;                       ws += (size_t)N * 64 * 4;
  float* xl2    = (float*)ws;                       ws += (size_t)N * 16 * 4;
  float* a_src2 = (float*)ws;                       ws += (size_t)N * 4;
  float* a_dst2 = (float*)ws;                       ws += (size_t)N * 4;
  int* deg      = (int*)ws;                         ws += (size_t)N * 4;
  int* rowptr   = (int*)ws;                         ws += (size_t)(N + 1) * 4;
  int* cursor   = (int*)ws;                         ws += (size_t)N * 4;
  int* srcs     = (int*)ws;                         ws += (size_t)(E + N) * 4;
  int* partials = (int*)ws;                         ws += (size_t)nb * 4;
  int* blockoff = (int*)ws;                         ws += (size_t)nb * 4;

  // CSR build (by destination), self-loops included via deg init = 1
  deg_init<<<(N + 255) / 256, 256, 0, stream>>>(deg, N);
  deg_hist<<<(E + 255) / 256, 256, 0, stream>>>(ei, deg, E);
  partial_sums<<<nb, 256, 0, stream>>>(deg, partials, N);
  scan_partials<<<1, 256, 0, stream>>>(partials, blockoff, rowptr, nb, N);
  scan_blocks<<<nb, 256, 0, stream>>>(deg, blockoff, rowptr, cursor, N);
  scatter_kernel<<<(E + N + 255) / 256, 256, 0, stream>>>(ei, cursor, srcs, E, N);

  // layer 1
  gemm1_kernel<<<(N + 63) / 64, 256, 0, stream>>>(x, W1, att_src1, att_dst1,
                                                  xlb, a_src1, a_dst1, N);
  agg1_csr<<<((size_t)N * 64 + 255) / 256, 256, 0, stream>>>(rowptr, srcs, a_src1, a_dst1,
                                                             xlb, agg1, N);

  // layer 2
  gemm2_prep<<<(N + 15) / 16, 256, 0, stream>>>(agg1, bias1, W2, att_src2, att_dst2,
                                                xl2, a_src2, a_dst2, N);
  agg2_fin<<<((size_t)N * 16 + 255) / 256, 256, 0, stream>>>(rowptr, srcs, a_src2, a_dst2,
                                                             xl2, bias2, out, N);
}

// Round 5
// 348.271 us; speedup vs baseline: 8.9998x; 1.0191x over previous
//
#include <hip/hip_runtime.h>
#include <math.h>

#define NEG_SLOPE 0.2f

typedef short short8 __attribute__((ext_vector_type(8)));
typedef float floatx4 __attribute__((ext_vector_type(4)));

static __device__ __forceinline__ float bf2f(unsigned short u) {
  return __uint_as_float(((unsigned int)u) << 16);
}
static __device__ __forceinline__ unsigned short f2bf(float f) {
  unsigned int u = __float_as_uint(f);
  u = (u + 0x7fffu + ((u >> 16) & 1u)) >> 16;  // RNE
  return (unsigned short)u;
}
static __device__ __forceinline__ unsigned int pack2(float a, float b) {
  return (unsigned int)f2bf(a) | ((unsigned int)f2bf(b) << 16);
}

// ---------- W1 [512][64] fp32 -> W1t [64][512] bf16 ----------
__global__ void conv_w1(const float* __restrict__ W1, unsigned short* __restrict__ W1t) {
  int i = blockIdx.x * 256 + threadIdx.x;  // 32768
  int k = i >> 6, c = i & 63;
  W1t[c * 512 + k] = f2bf(W1[i]);
}

// ---------- GEMM1 via MFMA: xl_bf16[M,64] = bf16(A[M,512]) @ W1t^T; fused att coefs ----------
// block: 256 thr = 4 waves; wave w owns rows [row0+16w, +16); 4 col-tiles of 16.
__global__ __launch_bounds__(256) void gemm1_mfma(const float* __restrict__ A,
                                                  const unsigned short* __restrict__ W1t,
                                                  const float* __restrict__ att_src,
                                                  const float* __restrict__ att_dst,
                                                  unsigned short* __restrict__ xlb,
                                                  float* __restrict__ a_src,
                                                  float* __restrict__ a_dst, int M) {
  __shared__ unsigned short As[64 * 72];  // [row][k], pad 72 (144B stride: 2-way=free)
  __shared__ unsigned short Bs[64 * 72];  // [col][k]
  int tid = threadIdx.x;
  int w = tid >> 6, lane = tid & 63;
  int q = lane >> 4, cl = lane & 15;
  int row0 = blockIdx.x << 6;
  floatx4 acc[4] = {};

  int sr = tid >> 2;            // staging row/col 0..63
  int skq = (tid & 3) << 4;     // k offset 0,16,32,48
  int arow = row0 + sr;
  const float* Aptr = A + (size_t)arow * 512 + skq;
  const unsigned short* Bptr = W1t + sr * 512 + skq;
  unsigned short* AsW = As + sr * 72 + skq;
  unsigned short* BsW = Bs + sr * 72 + skq;

  for (int k0 = 0; k0 < 512; k0 += 64) {
    // issue global loads (regs) before barrier
    float4 f0 = make_float4(0.f, 0.f, 0.f, 0.f), f1 = f0, f2 = f0, f3 = f0;
    if (arow < M) {
      f0 = *(const float4*)(Aptr + k0);
      f1 = *(const float4*)(Aptr + k0 + 4);
      f2 = *(const float4*)(Aptr + k0 + 8);
      f3 = *(const float4*)(Aptr + k0 + 12);
    }
    uint4 b0 = *(const uint4*)(Bptr + k0);
    uint4 b1 = *(const uint4*)(Bptr + k0 + 8);
    __syncthreads();  // previous chunk's LDS reads complete
    uint4 a0, a1;
    a0.x = pack2(f0.x, f0.y); a0.y = pack2(f0.z, f0.w);
    a0.z = pack2(f1.x, f1.y); a0.w = pack2(f1.z, f1.w);
    a1.x = pack2(f2.x, f2.y); a1.y = pack2(f2.z, f2.w);
    a1.z = pack2(f3.x, f3.y); a1.w = pack2(f3.z, f3.w);
    *(uint4*)(AsW) = a0;
    *(uint4*)(AsW + 8) = a1;
    *(uint4*)(BsW) = b0;
    *(uint4*)(BsW + 8) = b1;
    __syncthreads();
#pragma unroll
    for (int kk = 0; kk < 2; ++kk) {
      short8 af = *(const short8*)(As + (w * 16 + cl) * 72 + kk * 32 + q * 8);
#pragma unroll
      for (int t = 0; t < 4; ++t) {
        short8 bf = *(const short8*)(Bs + (t * 16 + cl) * 72 + kk * 32 + q * 8);
        acc[t] = __builtin_amdgcn_mfma_f32_16x16x32_bf16(af, bf, acc[t], 0, 0, 0);
      }
    }
  }

  // epilogue: C/D layout col = cl (within tile), row = q*4 + reg
  float asv[4], adv[4];
#pragma unroll
  for (int t = 0; t < 4; ++t) {
    asv[t] = att_src[t * 16 + cl];
    adv[t] = att_dst[t * 16 + cl];
  }
#pragma unroll
  for (int reg = 0; reg < 4; ++reg) {
    int r = row0 + w * 16 + q * 4 + reg;
    bool ok = r < M;
#pragma unroll
    for (int t = 0; t < 4; ++t) {
      float v = acc[t][reg];
      if (ok) xlb[(size_t)r * 64 + t * 16 + cl] = f2bf(v);
      float ps = v * asv[t];
      float pd = v * adv[t];
      ps += __shfl_xor(ps, 1); pd += __shfl_xor(pd, 1);
      ps += __shfl_xor(ps, 2); pd += __shfl_xor(pd, 2);
      ps += __shfl_xor(ps, 4); pd += __shfl_xor(pd, 4);
      if (ok && (cl & 7) == 0) {
        int h = t * 2 + (cl >> 3);
        a_src[r * 8 + h] = ps;
        a_dst[r * 8 + h] = pd;
      }
    }
  }
}

// ---------- CSR build ----------
__global__ void deg_init(int* __restrict__ deg, int N) {
  int n = blockIdx.x * blockDim.x + threadIdx.x;
  if (n < N) deg[n] = 1;  // self-loop
}

__global__ void deg_hist(const int* __restrict__ ei, int* __restrict__ deg, int E) {
  int e = blockIdx.x * blockDim.x + threadIdx.x;
  if (e < E) atomicAdd(&deg[ei[E + e]], 1);
}

// hierarchical scan, chunk = 512 elements per 256-thread block
__global__ __launch_bounds__(256) void partial_sums(const int* __restrict__ deg,
                                                    int* __restrict__ partials, int N) {
  __shared__ int ws[4];
  int base = blockIdx.x * 512;
  int tid = threadIdx.x;
  int i0 = base + tid * 2;
  int s = 0;
  if (i0 < N) s += deg[i0];
  if (i0 + 1 < N) s += deg[i0 + 1];
#pragma unroll
  for (int off = 32; off >= 1; off >>= 1) s += __shfl_xor(s, off, 64);
  if ((tid & 63) == 0) ws[tid >> 6] = s;
  __syncthreads();
  if (tid == 0) partials[blockIdx.x] = ws[0] + ws[1] + ws[2] + ws[3];
}

__global__ __launch_bounds__(256) void scan_partials(const int* __restrict__ partials,
                                                     int* __restrict__ blockoff,
                                                     int* __restrict__ rowptr, int nb, int N) {
  __shared__ int sums[256];
  int tid = threadIdx.x;
  int chunk = (nb + 255) >> 8;
  int start = tid * chunk, end = min(start + chunk, nb);
  int s = 0;
  for (int i = start; i < end; ++i) s += partials[i];
  sums[tid] = s;
  __syncthreads();
  for (int off = 1; off < 256; off <<= 1) {
    int t = (tid >= off) ? sums[tid - off] : 0;
    __syncthreads();
    sums[tid] += t;
    __syncthreads();
  }
  int run = (tid == 0) ? 0 : sums[tid - 1];
  for (int i = start; i < end; ++i) {
    blockoff[i] = run;
    run += partials[i];
  }
  if (tid == 255) rowptr[N] = sums[255];
}

__global__ __launch_bounds__(256) void scan_blocks(const int* __restrict__ deg,
                                                   const int* __restrict__ blockoff,
                                                   int* __restrict__ rowptr,
                                                   int* __restrict__ cursor, int N) {
  __shared__ int wavesum[4];
  int base = blockIdx.x * 512;
  int tid = threadIdx.x;
  int lane = tid & 63, wv = tid >> 6;
  int i0 = base + tid * 2;
  int d0 = (i0 < N) ? deg[i0] : 0;
  int d1 = (i0 + 1 < N) ? deg[i0 + 1] : 0;
  int s = d0 + d1;
  int v = s;
#pragma unroll
  for (int off = 1; off < 64; off <<= 1) {
    int t = __shfl_up(v, off, 64);
    if (lane >= off) v += t;
  }
  if (lane == 63) wavesum[wv] = v;
  __syncthreads();
  int woff = 0;
  for (int w = 0; w < wv; ++w) woff += wavesum[w];
  int excl = v - s + woff + blockoff[blockIdx.x];
  if (i0 < N) { rowptr[i0] = excl; cursor[i0] = excl; }
  if (i0 + 1 < N) { rowptr[i0 + 1] = excl + d0; cursor[i0 + 1] = excl + d0; }
}

__global__ void scatter_kernel(const int* __restrict__ ei, int* __restrict__ cursor,
                               int* __restrict__ srcs, int E, int N) {
  int i = blockIdx.x * blockDim.x + threadIdx.x;
  if (i >= E + N) return;
  int s, d;
  if (i < E) { s = ei[i]; d = ei[E + i]; } else { s = d = i - E; }
  int pos = atomicAdd(&cursor[d], 1);
  srcs[pos] = s;
}

// ---------- layer-1 aggregation: one 64-lane wave per dst node ----------
__global__ __launch_bounds__(256) void agg1_csr(const int* __restrict__ rowptr,
                                                const int* __restrict__ srcs,
                                                const float* __restrict__ a_src,
                                                const float* __restrict__ a_dst,
                                                const unsigned short* __restrict__ xlb,
                                                float* __restrict__ agg1, int N) {
  int wave = (blockIdx.x * blockDim.x + threadIdx.x) >> 6;
  int lane = threadIdx.x & 63;
  if (wave >= N) return;
  int h = lane >> 3;
  int beg = rowptr[wave], end = rowptr[wave + 1];
  float ad = a_dst[wave * 8 + h];
  float den = 0.f, acc = 0.f;
  int p = beg;
  for (; p + 4 <= end; p += 4) {
    int s0 = srcs[p], s1 = srcs[p + 1], s2 = srcs[p + 2], s3 = srcs[p + 3];
    float a0 = a_src[s0 * 8 + h], a1 = a_src[s1 * 8 + h];
    float a2 = a_src[s2 * 8 + h], a3 = a_src[s3 * 8 + h];
    float x0 = bf2f(xlb[(size_t)s0 * 64 + lane]);
    float x1 = bf2f(xlb[(size_t)s1 * 64 + lane]);
    float x2 = bf2f(xlb[(size_t)s2 * 64 + lane]);
    float x3 = bf2f(xlb[(size_t)s3 * 64 + lane]);
    a0 += ad; a1 += ad; a2 += ad; a3 += ad;
    a0 = a0 >= 0.f ? a0 : NEG_SLOPE * a0;
    a1 = a1 >= 0.f ? a1 : NEG_SLOPE * a1;
    a2 = a2 >= 0.f ? a2 : NEG_SLOPE * a2;
    a3 = a3 >= 0.f ? a3 : NEG_SLOPE * a3;
    float w0 = __expf(a0), w1 = __expf(a1), w2 = __expf(a2), w3 = __expf(a3);
    den += (w0 + w1) + (w2 + w3);
    acc += w0 * x0 + w1 * x1 + w2 * x2 + w3 * x3;
  }
  for (; p < end; ++p) {
    int s = srcs[p];
    float a = a_src[s * 8 + h] + ad;
    a = a >= 0.f ? a : NEG_SLOPE * a;
    float w = __expf(a);
    den += w;
    acc += w * bf2f(xlb[(size_t)s * 64 + lane]);
  }
  agg1[(size_t)wave * 64 + lane] = acc / (den + 1e-16f);
}

// ---------- layer-2 GEMM (bias1 fused) + attention coefs ----------
__global__ __launch_bounds__(256) void gemm2_prep(const float* __restrict__ agg1,
                                                  const float* __restrict__ bias1,
                                                  const float* __restrict__ W2,
                                                  const float* __restrict__ att_src2,
                                                  const float* __restrict__ att_dst2,
                                                  float* __restrict__ xl2,
                                                  float* __restrict__ a_src2,
                                                  float* __restrict__ a_dst2, int N) {
  __shared__ float hs[16 * 68];
  int tid = threadIdx.x;
  int n0 = blockIdx.x << 4;
  {
    int node = tid >> 4;
    int off = (tid & 15) << 2;
    int nn = n0 + node;
    float4 v = make_float4(0.f, 0.f, 0.f, 0.f);
    if (nn < N) {
      v = *(const float4*)(agg1 + (size_t)nn * 64 + off);
      float4 b = *(const float4*)(bias1 + off);
      v.x += b.x; v.y += b.y; v.z += b.z; v.w += b.w;
    }
    *(float4*)(hs + node * 68 + off) = v;
  }
  __syncthreads();
  int t = tid >> 4, c = tid & 15;
  int n = n0 + t;
  if (n >= N) return;
  float sum = 0.f;
#pragma unroll
  for (int k = 0; k < 64; ++k) sum += hs[t * 68 + k] * W2[k * 16 + c];
  xl2[(size_t)n * 16 + c] = sum;
  float ps = sum * att_src2[c];
  float pd = sum * att_dst2[c];
#pragma unroll
  for (int w = 8; w >= 1; w >>= 1) {
    ps += __shfl_xor(ps, w, 16);
    pd += __shfl_xor(pd, w, 16);
  }
  if (c == 0) {
    a_src2[n] = ps;
    a_dst2[n] = pd;
  }
}

// ---------- layer-2 aggregation + bias2 + ELU + log_softmax ----------
__global__ __launch_bounds__(256) void agg2_fin(const int* __restrict__ rowptr,
                                                const int* __restrict__ srcs,
                                                const float* __restrict__ a_src2,
                                                const float* __restrict__ a_dst2,
                                                const float* __restrict__ xl2,
                                                const float* __restrict__ bias2,
                                                float* __restrict__ out, int N) {
  int t = blockIdx.x * blockDim.x + threadIdx.x;
  int node = t >> 4;
  int c = t & 15;
  if (node >= N) return;
  int beg = rowptr[node], end = rowptr[node + 1];
  float ad = a_dst2[node];
  float den = 0.f, acc = 0.f;
  int p = beg;
  for (; p + 4 <= end; p += 4) {
    int s0 = srcs[p], s1 = srcs[p + 1], s2 = srcs[p + 2], s3 = srcs[p + 3];
    float a0 = a_src2[s0], a1 = a_src2[s1], a2 = a_src2[s2], a3 = a_src2[s3];
    float x0 = xl2[(size_t)s0 * 16 + c], x1 = xl2[(size_t)s1 * 16 + c];
    float x2 = xl2[(size_t)s2 * 16 + c], x3 = xl2[(size_t)s3 * 16 + c];
    a0 += ad; a1 += ad; a2 += ad; a3 += ad;
    a0 = a0 >= 0.f ? a0 : NEG_SLOPE * a0;
    a1 = a1 >= 0.f ? a1 : NEG_SLOPE * a1;
    a2 = a2 >= 0.f ? a2 : NEG_SLOPE * a2;
    a3 = a3 >= 0.f ? a3 : NEG_SLOPE * a3;
    float w0 = __expf(a0), w1 = __expf(a1), w2 = __expf(a2), w3 = __expf(a3);
    den += (w0 + w1) + (w2 + w3);
    acc += w0 * x0 + w1 * x1 + w2 * x2 + w3 * x3;
  }
  for (; p < end; ++p) {
    int s = srcs[p];
    float a = a_src2[s] + ad;
    a = a >= 0.f ? a : NEG_SLOPE * a;
    float w = __expf(a);
    den += w;
    acc += w * xl2[(size_t)s * 16 + c];
  }
  float o = acc / (den + 1e-16f) + bias2[c];
  o = o > 0.f ? o : expm1f(o);  // ELU alpha=1
  float mx = o;
#pragma unroll
  for (int w = 8; w >= 1; w >>= 1) mx = fmaxf(mx, __shfl_xor(mx, w, 16));
  float e = __expf(o - mx);
  float ssum = e;
#pragma unroll
  for (int w = 8; w >= 1; w >>= 1) ssum += __shfl_xor(ssum, w, 16);
  out[(size_t)node * 16 + c] = o - mx - logf(ssum);
}

extern "C" void kernel_launch(void* const* d_in, const int* in_sizes, int n_in,
                              void* d_out, int out_size, void* d_ws, size_t ws_size,
                              hipStream_t stream) {
  const float* x        = (const float*)d_in[0];
  const int*   ei       = (const int*)d_in[1];
  const float* W1       = (const float*)d_in[2];
  const float* att_src1 = (const float*)d_in[3];
  const float* att_dst1 = (const float*)d_in[4];
  const float* bias1    = (const float*)d_in[5];
  const float* W2       = (const float*)d_in[6];
  const float* att_src2 = (const float*)d_in[7];
  const float* att_dst2 = (const float*)d_in[8];
  const float* bias2    = (const float*)d_in[9];
  float* out = (float*)d_out;

  int N = in_sizes[0] / 512;
  int E = in_sizes[1] / 2;
  int nb = (N + 511) / 512;

  char* ws = (char*)d_ws;
  unsigned short* xlb = (unsigned short*)ws;        ws += (size_t)N * 64 * 2;
  unsigned short* W1t = (unsigned short*)ws;        ws += (size_t)512 * 64 * 2;
  float* a_src1 = (float*)ws;                       ws += (size_t)N * 8 * 4;
  float* a_dst1 = (float*)ws;                       ws += (size_t)N * 8 * 4;
  float* agg1   = (float*)ws;                       ws += (size_t)N * 64 * 4;
  float* xl2    = (float*)ws;                       ws += (size_t)N * 16 * 4;
  float* a_src2 = (float*)ws;                       ws += (size_t)N * 4;
  float* a_dst2 = (float*)ws;                       ws += (size_t)N * 4;
  int* deg      = (int*)ws;                         ws += (size_t)N * 4;
  int* rowptr   = (int*)ws;                         ws += (size_t)(N + 1) * 4;
  int* cursor   = (int*)ws;                         ws += (size_t)N * 4;
  int* srcs     = (int*)ws;                         ws += (size_t)(E + N) * 4;
  int* partials = (int*)ws;                         ws += (size_t)nb * 4;
  int* blockoff = (int*)ws;                         ws += (size_t)nb * 4;

  // CSR build (by destination), self-loops included via deg init = 1
  deg_init<<<(N + 255) / 256, 256, 0, stream>>>(deg, N);
  deg_hist<<<(E + 255) / 256, 256, 0, stream>>>(ei, deg, E);
  partial_sums<<<nb, 256, 0, stream>>>(deg, partials, N);
  scan_partials<<<1, 256, 0, stream>>>(partials, blockoff, rowptr, nb, N);
  scan_blocks<<<nb, 256, 0, stream>>>(deg, blockoff, rowptr, cursor, N);
  scatter_kernel<<<(E + N + 255) / 256, 256, 0, stream>>>(ei, cursor, srcs, E, N);

  // layer 1
  conv_w1<<<128, 256, 0, stream>>>(W1, W1t);
  gemm1_mfma<<<(N + 63) / 64, 256, 0, stream>>>(x, W1t, att_src1, att_dst1,
                                                xlb, a_src1, a_dst1, N);
  agg1_csr<<<((size_t)N * 64 + 255) / 256, 256, 0, stream>>>(rowptr, srcs, a_src1, a_dst1,
                                                             xlb, agg1, N);

  // layer 2
  gemm2_prep<<<(N + 15) / 16, 256, 0, stream>>>(agg1, bias1, W2, att_src2, att_dst2,
                                                xl2, a_src2, a_dst2, N);
  agg2_fin<<<((size_t)N * 16 + 255) / 256, 256, 0, stream>>>(rowptr, srcs, a_src2, a_dst2,
                                                             xl2, bias2, out, N);
}

// Round 6
// 329.645 us; speedup vs baseline: 9.5083x; 1.0565x over previous
//
#include <hip/hip_runtime.h>
#include <math.h>

#define NEG_SLOPE 0.2f

typedef short short8 __attribute__((ext_vector_type(8)));
typedef float floatx4 __attribute__((ext_vector_type(4)));

static __device__ __forceinline__ float bf2f(unsigned short u) {
  return __uint_as_float(((unsigned int)u) << 16);
}
static __device__ __forceinline__ unsigned short f2bf(float f) {
  unsigned int u = __float_as_uint(f);
  u = (u + 0x7fffu + ((u >> 16) & 1u)) >> 16;  // RNE
  return (unsigned short)u;
}
static __device__ __forceinline__ unsigned int pack2(float a, float b) {
  return (unsigned int)f2bf(a) | ((unsigned int)f2bf(b) << 16);
}

// ---------- W1 [512][64] fp32 -> W1t [64][512] bf16 ----------
__global__ void conv_w1(const float* __restrict__ W1, unsigned short* __restrict__ W1t) {
  int i = blockIdx.x * 256 + threadIdx.x;  // 32768
  int k = i >> 6, c = i & 63;
  W1t[c * 512 + k] = f2bf(W1[i]);
}

// ---------- GEMM1 via MFMA ----------
__global__ __launch_bounds__(256) void gemm1_mfma(const float* __restrict__ A,
                                                  const unsigned short* __restrict__ W1t,
                                                  const float* __restrict__ att_src,
                                                  const float* __restrict__ att_dst,
                                                  unsigned short* __restrict__ xlb,
                                                  float* __restrict__ a_src,
                                                  float* __restrict__ a_dst, int M) {
  __shared__ unsigned short As[64 * 72];  // [row][k], pad 72 (2-way bank alias = free)
  __shared__ unsigned short Bs[64 * 72];  // [col][k]
  int tid = threadIdx.x;
  int w = tid >> 6, lane = tid & 63;
  int q = lane >> 4, cl = lane & 15;
  int row0 = blockIdx.x << 6;
  floatx4 acc[4] = {};

  int sr = tid >> 2;            // staging row/col 0..63
  int skq = (tid & 3) << 4;     // k offset 0,16,32,48
  int arow = row0 + sr;
  const float* Aptr = A + (size_t)arow * 512 + skq;
  const unsigned short* Bptr = W1t + sr * 512 + skq;
  unsigned short* AsW = As + sr * 72 + skq;
  unsigned short* BsW = Bs + sr * 72 + skq;

  for (int k0 = 0; k0 < 512; k0 += 64) {
    float4 f0 = make_float4(0.f, 0.f, 0.f, 0.f), f1 = f0, f2 = f0, f3 = f0;
    if (arow < M) {
      f0 = *(const float4*)(Aptr + k0);
      f1 = *(const float4*)(Aptr + k0 + 4);
      f2 = *(const float4*)(Aptr + k0 + 8);
      f3 = *(const float4*)(Aptr + k0 + 12);
    }
    uint4 b0 = *(const uint4*)(Bptr + k0);
    uint4 b1 = *(const uint4*)(Bptr + k0 + 8);
    __syncthreads();
    uint4 a0, a1;
    a0.x = pack2(f0.x, f0.y); a0.y = pack2(f0.z, f0.w);
    a0.z = pack2(f1.x, f1.y); a0.w = pack2(f1.z, f1.w);
    a1.x = pack2(f2.x, f2.y); a1.y = pack2(f2.z, f2.w);
    a1.z = pack2(f3.x, f3.y); a1.w = pack2(f3.z, f3.w);
    *(uint4*)(AsW) = a0;
    *(uint4*)(AsW + 8) = a1;
    *(uint4*)(BsW) = b0;
    *(uint4*)(BsW + 8) = b1;
    __syncthreads();
#pragma unroll
    for (int kk = 0; kk < 2; ++kk) {
      short8 af = *(const short8*)(As + (w * 16 + cl) * 72 + kk * 32 + q * 8);
#pragma unroll
      for (int t = 0; t < 4; ++t) {
        short8 bf = *(const short8*)(Bs + (t * 16 + cl) * 72 + kk * 32 + q * 8);
        acc[t] = __builtin_amdgcn_mfma_f32_16x16x32_bf16(af, bf, acc[t], 0, 0, 0);
      }
    }
  }

  float asv[4], adv[4];
#pragma unroll
  for (int t = 0; t < 4; ++t) {
    asv[t] = att_src[t * 16 + cl];
    adv[t] = att_dst[t * 16 + cl];
  }
#pragma unroll
  for (int reg = 0; reg < 4; ++reg) {
    int r = row0 + w * 16 + q * 4 + reg;
    bool ok = r < M;
#pragma unroll
    for (int t = 0; t < 4; ++t) {
      float v = acc[t][reg];
      if (ok) xlb[(size_t)r * 64 + t * 16 + cl] = f2bf(v);
      float ps = v * asv[t];
      float pd = v * adv[t];
      ps += __shfl_xor(ps, 1); pd += __shfl_xor(pd, 1);
      ps += __shfl_xor(ps, 2); pd += __shfl_xor(pd, 2);
      ps += __shfl_xor(ps, 4); pd += __shfl_xor(pd, 4);
      if (ok && (cl & 7) == 0) {
        int h = t * 2 + (cl >> 3);
        a_src[r * 8 + h] = ps;
        a_dst[r * 8 + h] = pd;
      }
    }
  }
}

// ---------- CSR build ----------
__global__ void deg_init(int* __restrict__ deg, int N) {
  int n = blockIdx.x * blockDim.x + threadIdx.x;
  if (n < N) deg[n] = 1;  // self-loop
}

// XCD-sliced histogram: workgroup b handles dst-slice (b&7) on edge chunk (b>>3).
// Heuristic: blockIdx%8 -> XCD round-robin, so each deg cacheline is touched by one XCD.
__global__ __launch_bounds__(256) void deg_hist_sliced(const int* __restrict__ ei,
                                                       int* __restrict__ deg,
                                                       int E, int N, int ipc) {
  int slice = blockIdx.x & 7;
  int chunk = blockIdx.x >> 3;
  int lo = (int)(((long long)slice * N) >> 3);
  int hi = (int)(((long long)(slice + 1) * N) >> 3);
  int beg = chunk * ipc;
  int end = min(beg + ipc, E);
  for (int i = beg + threadIdx.x; i < end; i += 256) {
    int d = ei[E + i];
    if (d >= lo && d < hi) atomicAdd(&deg[d], 1);
  }
}

// hierarchical scan, chunk = 512 elements per 256-thread block
__global__ __launch_bounds__(256) void partial_sums(const int* __restrict__ deg,
                                                    int* __restrict__ partials, int N) {
  __shared__ int ws[4];
  int base = blockIdx.x * 512;
  int tid = threadIdx.x;
  int i0 = base + tid * 2;
  int s = 0;
  if (i0 < N) s += deg[i0];
  if (i0 + 1 < N) s += deg[i0 + 1];
#pragma unroll
  for (int off = 32; off >= 1; off >>= 1) s += __shfl_xor(s, off, 64);
  if ((tid & 63) == 0) ws[tid >> 6] = s;
  __syncthreads();
  if (tid == 0) partials[blockIdx.x] = ws[0] + ws[1] + ws[2] + ws[3];
}

__global__ __launch_bounds__(256) void scan_partials(const int* __restrict__ partials,
                                                     int* __restrict__ blockoff,
                                                     int* __restrict__ rowptr, int nb, int N) {
  __shared__ int sums[256];
  int tid = threadIdx.x;
  int chunk = (nb + 255) >> 8;
  int start = tid * chunk, end = min(start + chunk, nb);
  int s = 0;
  for (int i = start; i < end; ++i) s += partials[i];
  sums[tid] = s;
  __syncthreads();
  for (int off = 1; off < 256; off <<= 1) {
    int t = (tid >= off) ? sums[tid - off] : 0;
    __syncthreads();
    sums[tid] += t;
    __syncthreads();
  }
  int run = (tid == 0) ? 0 : sums[tid - 1];
  for (int i = start; i < end; ++i) {
    blockoff[i] = run;
    run += partials[i];
  }
  if (tid == 255) rowptr[N] = sums[255];
}

__global__ __launch_bounds__(256) void scan_blocks(const int* __restrict__ deg,
                                                   const int* __restrict__ blockoff,
                                                   int* __restrict__ rowptr,
                                                   int* __restrict__ cursor, int N) {
  __shared__ int wavesum[4];
  int base = blockIdx.x * 512;
  int tid = threadIdx.x;
  int lane = tid & 63, wv = tid >> 6;
  int i0 = base + tid * 2;
  int d0 = (i0 < N) ? deg[i0] : 0;
  int d1 = (i0 + 1 < N) ? deg[i0 + 1] : 0;
  int s = d0 + d1;
  int v = s;
#pragma unroll
  for (int off = 1; off < 64; off <<= 1) {
    int t = __shfl_up(v, off, 64);
    if (lane >= off) v += t;
  }
  if (lane == 63) wavesum[wv] = v;
  __syncthreads();
  int woff = 0;
  for (int w = 0; w < wv; ++w) woff += wavesum[w];
  int excl = v - s + woff + blockoff[blockIdx.x];
  if (i0 < N) { rowptr[i0] = excl; cursor[i0] = excl; }
  if (i0 + 1 < N) { rowptr[i0 + 1] = excl + d0; cursor[i0 + 1] = excl + d0; }
}

// XCD-sliced scatter: same slicing as deg_hist_sliced. Each slice's srcs
// positions are a contiguous range (positions monotone in dst) -> lines fill
// inside one XCD's L2 and evict once.
__global__ __launch_bounds__(256) void scatter_sliced(const int* __restrict__ ei,
                                                      int* __restrict__ cursor,
                                                      int* __restrict__ srcs,
                                                      int E, int N, int ipc) {
  int slice = blockIdx.x & 7;
  int chunk = blockIdx.x >> 3;
  int lo = (int)(((long long)slice * N) >> 3);
  int hi = (int)(((long long)(slice + 1) * N) >> 3);
  int total = E + N;
  int beg = chunk * ipc;
  int end = min(beg + ipc, total);
  for (int i = beg + threadIdx.x; i < end; i += 256) {
    int d = (i < E) ? ei[E + i] : (i - E);
    if (d >= lo && d < hi) {
      int s = (i < E) ? ei[i] : d;
      int pos = atomicAdd(&cursor[d], 1);
      srcs[pos] = s;
    }
  }
}

// ---------- layer-1 aggregation: one 64-lane wave per dst node ----------
__global__ __launch_bounds__(256) void agg1_csr(const int* __restrict__ rowptr,
                                                const int* __restrict__ srcs,
                                                const float* __restrict__ a_src,
                                                const float* __restrict__ a_dst,
                                                const unsigned short* __restrict__ xlb,
                                                float* __restrict__ agg1, int N) {
  int wave = (blockIdx.x * blockDim.x + threadIdx.x) >> 6;
  int lane = threadIdx.x & 63;
  if (wave >= N) return;
  int h = lane >> 3;
  int beg = rowptr[wave], end = rowptr[wave + 1];
  float ad = a_dst[wave * 8 + h];
  float den = 0.f, acc = 0.f;
  int p = beg;
  for (; p + 4 <= end; p += 4) {
    int s0 = srcs[p], s1 = srcs[p + 1], s2 = srcs[p + 2], s3 = srcs[p + 3];
    float a0 = a_src[s0 * 8 + h], a1 = a_src[s1 * 8 + h];
    float a2 = a_src[s2 * 8 + h], a3 = a_src[s3 * 8 + h];
    float x0 = bf2f(xlb[(size_t)s0 * 64 + lane]);
    float x1 = bf2f(xlb[(size_t)s1 * 64 + lane]);
    float x2 = bf2f(xlb[(size_t)s2 * 64 + lane]);
    float x3 = bf2f(xlb[(size_t)s3 * 64 + lane]);
    a0 += ad; a1 += ad; a2 += ad; a3 += ad;
    a0 = a0 >= 0.f ? a0 : NEG_SLOPE * a0;
    a1 = a1 >= 0.f ? a1 : NEG_SLOPE * a1;
    a2 = a2 >= 0.f ? a2 : NEG_SLOPE * a2;
    a3 = a3 >= 0.f ? a3 : NEG_SLOPE * a3;
    float w0 = __expf(a0), w1 = __expf(a1), w2 = __expf(a2), w3 = __expf(a3);
    den += (w0 + w1) + (w2 + w3);
    acc += w0 * x0 + w1 * x1 + w2 * x2 + w3 * x3;
  }
  for (; p < end; ++p) {
    int s = srcs[p];
    float a = a_src[s * 8 + h] + ad;
    a = a >= 0.f ? a : NEG_SLOPE * a;
    float w = __expf(a);
    den += w;
    acc += w * bf2f(xlb[(size_t)s * 64 + lane]);
  }
  agg1[(size_t)wave * 64 + lane] = acc / (den + 1e-16f);
}

// ---------- layer-2 GEMM (bias1 fused) + attention coefs ----------
__global__ __launch_bounds__(256) void gemm2_prep(const float* __restrict__ agg1,
                                                  const float* __restrict__ bias1,
                                                  const float* __restrict__ W2,
                                                  const float* __restrict__ att_src2,
                                                  const float* __restrict__ att_dst2,
                                                  float* __restrict__ xl2,
                                                  float* __restrict__ a_src2,
                                                  float* __restrict__ a_dst2, int N) {
  __shared__ float hs[16 * 68];
  int tid = threadIdx.x;
  int n0 = blockIdx.x << 4;
  {
    int node = tid >> 4;
    int off = (tid & 15) << 2;
    int nn = n0 + node;
    float4 v = make_float4(0.f, 0.f, 0.f, 0.f);
    if (nn < N) {
      v = *(const float4*)(agg1 + (size_t)nn * 64 + off);
      float4 b = *(const float4*)(bias1 + off);
      v.x += b.x; v.y += b.y; v.z += b.z; v.w += b.w;
    }
    *(float4*)(hs + node * 68 + off) = v;
  }
  __syncthreads();
  int t = tid >> 4, c = tid & 15;
  int n = n0 + t;
  if (n >= N) return;
  float sum = 0.f;
#pragma unroll
  for (int k = 0; k < 64; ++k) sum += hs[t * 68 + k] * W2[k * 16 + c];
  xl2[(size_t)n * 16 + c] = sum;
  float ps = sum * att_src2[c];
  float pd = sum * att_dst2[c];
#pragma unroll
  for (int w = 8; w >= 1; w >>= 1) {
    ps += __shfl_xor(ps, w, 16);
    pd += __shfl_xor(pd, w, 16);
  }
  if (c == 0) {
    a_src2[n] = ps;
    a_dst2[n] = pd;
  }
}

// ---------- layer-2 aggregation + bias2 + ELU + log_softmax ----------
__global__ __launch_bounds__(256) void agg2_fin(const int* __restrict__ rowptr,
                                                const int* __restrict__ srcs,
                                                const float* __restrict__ a_src2,
                                                const float* __restrict__ a_dst2,
                                                const float* __restrict__ xl2,
                                                const float* __restrict__ bias2,
                                                float* __restrict__ out, int N) {
  int t = blockIdx.x * blockDim.x + threadIdx.x;
  int node = t >> 4;
  int c = t & 15;
  if (node >= N) return;
  int beg = rowptr[node], end = rowptr[node + 1];
  float ad = a_dst2[node];
  float den = 0.f, acc = 0.f;
  int p = beg;
  for (; p + 4 <= end; p += 4) {
    int s0 = srcs[p], s1 = srcs[p + 1], s2 = srcs[p + 2], s3 = srcs[p + 3];
    float a0 = a_src2[s0], a1 = a_src2[s1], a2 = a_src2[s2], a3 = a_src2[s3];
    float x0 = xl2[(size_t)s0 * 16 + c], x1 = xl2[(size_t)s1 * 16 + c];
    float x2 = xl2[(size_t)s2 * 16 + c], x3 = xl2[(size_t)s3 * 16 + c];
    a0 += ad; a1 += ad; a2 += ad; a3 += ad;
    a0 = a0 >= 0.f ? a0 : NEG_SLOPE * a0;
    a1 = a1 >= 0.f ? a1 : NEG_SLOPE * a1;
    a2 = a2 >= 0.f ? a2 : NEG_SLOPE * a2;
    a3 = a3 >= 0.f ? a3 : NEG_SLOPE * a3;
    float w0 = __expf(a0), w1 = __expf(a1), w2 = __expf(a2), w3 = __expf(a3);
    den += (w0 + w1) + (w2 + w3);
    acc += w0 * x0 + w1 * x1 + w2 * x2 + w3 * x3;
  }
  for (; p < end; ++p) {
    int s = srcs[p];
    float a = a_src2[s] + ad;
    a = a >= 0.f ? a : NEG_SLOPE * a;
    float w = __expf(a);
    den += w;
    acc += w * xl2[(size_t)s * 16 + c];
  }
  float o = acc / (den + 1e-16f) + bias2[c];
  o = o > 0.f ? o : expm1f(o);  // ELU alpha=1
  float mx = o;
#pragma unroll
  for (int w = 8; w >= 1; w >>= 1) mx = fmaxf(mx, __shfl_xor(mx, w, 16));
  float e = __expf(o - mx);
  float ssum = e;
#pragma unroll
  for (int w = 8; w >= 1; w >>= 1) ssum += __shfl_xor(ssum, w, 16);
  out[(size_t)node * 16 + c] = o - mx - logf(ssum);
}

extern "C" void kernel_launch(void* const* d_in, const int* in_sizes, int n_in,
                              void* d_out, int out_size, void* d_ws, size_t ws_size,
                              hipStream_t stream) {
  const float* x        = (const float*)d_in[0];
  const int*   ei       = (const int*)d_in[1];
  const float* W1       = (const float*)d_in[2];
  const float* att_src1 = (const float*)d_in[3];
  const float* att_dst1 = (const float*)d_in[4];
  const float* bias1    = (const float*)d_in[5];
  const float* W2       = (const float*)d_in[6];
  const float* att_src2 = (const float*)d_in[7];
  const float* att_dst2 = (const float*)d_in[8];
  const float* bias2    = (const float*)d_in[9];
  float* out = (float*)d_out;

  int N = in_sizes[0] / 512;
  int E = in_sizes[1] / 2;
  int nb = (N + 511) / 512;

  char* ws = (char*)d_ws;
  unsigned short* xlb = (unsigned short*)ws;        ws += (size_t)N * 64 * 2;
  unsigned short* W1t = (unsigned short*)ws;        ws += (size_t)512 * 64 * 2;
  float* a_src1 = (float*)ws;                       ws += (size_t)N * 8 * 4;
  float* a_dst1 = (float*)ws;                       ws += (size_t)N * 8 * 4;
  float* agg1   = (float*)ws;                       ws += (size_t)N * 64 * 4;
  float* xl2    = (float*)ws;                       ws += (size_t)N * 16 * 4;
  float* a_src2 = (float*)ws;                       ws += (size_t)N * 4;
  float* a_dst2 = (float*)ws;                       ws += (size_t)N * 4;
  int* deg      = (int*)ws;                         ws += (size_t)N * 4;
  int* rowptr   = (int*)ws;                         ws += (size_t)(N + 1) * 4;
  int* cursor   = (int*)ws;                         ws += (size_t)N * 4;
  int* srcs     = (int*)ws;                         ws += (size_t)(E + N) * 4;
  int* partials = (int*)ws;                         ws += (size_t)nb * 4;
  int* blockoff = (int*)ws;                         ws += (size_t)nb * 4;

  // CSR build (by destination), XCD-sliced to kill write amplification
  const int NCHUNK = 256;
  int ipc_h = (E + NCHUNK - 1) / NCHUNK;
  int ipc_s = (E + N + NCHUNK - 1) / NCHUNK;
  deg_init<<<(N + 255) / 256, 256, 0, stream>>>(deg, N);
  deg_hist_sliced<<<NCHUNK * 8, 256, 0, stream>>>(ei, deg, E, N, ipc_h);
  partial_sums<<<nb, 256, 0, stream>>>(deg, partials, N);
  scan_partials<<<1, 256, 0, stream>>>(partials, blockoff, rowptr, nb, N);
  scan_blocks<<<nb, 256, 0, stream>>>(deg, blockoff, rowptr, cursor, N);
  scatter_sliced<<<NCHUNK * 8, 256, 0, stream>>>(ei, cursor, srcs, E, N, ipc_s);

  // layer 1
  conv_w1<<<128, 256, 0, stream>>>(W1, W1t);
  gemm1_mfma<<<(N + 63) / 64, 256, 0, stream>>>(x, W1t, att_src1, att_dst1,
                                                xlb, a_src1, a_dst1, N);
  agg1_csr<<<((size_t)N * 64 + 255) / 256, 256, 0, stream>>>(rowptr, srcs, a_src1, a_dst1,
                                                             xlb, agg1, N);

  // layer 2
  gemm2_prep<<<(N + 15) / 16, 256, 0, stream>>>(agg1, bias1, W2, att_src2, att_dst2,
                                                xl2, a_src2, a_dst2, N);
  agg2_fin<<<((size_t)N * 16 + 255) / 256, 256, 0, stream>>>(rowptr, srcs, a_src2, a_dst2,
                                                             xl2, bias2, out, N);
}